// Round 14
// baseline (4131.107 us; speedup 1.0000x reference)
//
#include <hip/hip_runtime.h>

#define BB 256
#define NN 512
#define DD 128
#define HH 8

static constexpr float NEGC = -1e9f;
static constexpr float INV_SQRT_D = 0.08838834764831845f; // 1/sqrt(128)

__device__ __forceinline__ float dot4(float4 a, float4 b) {
    return a.x * b.x + a.y * b.y + a.z * b.z + a.w * b.w;
}
__device__ __forceinline__ void fma4(float4& a, float p, float4 e) {
    a.x += p * e.x; a.y += p * e.y; a.z += p * e.z; a.w += p * e.w;
}

// ---------------- precompute: fixed_ctx = mean_n(E) @ W_fixed ----------------
__global__ __launch_bounds__(128)
void precompute_fc(const float* __restrict__ E, const float* __restrict__ Wf,
                   float* __restrict__ fc) {
    int b = blockIdx.x, d = threadIdx.x;
    __shared__ float ge[DD];
    const float* Eb = E + (size_t)b * NN * DD;
    float s = 0.f;
    for (int n = 0; n < NN; ++n) s += Eb[n * DD + d];
    ge[d] = s * (1.0f / 512.0f);
    __syncthreads();
    float o = 0.f;
    for (int k = 0; k < DD; ++k) o += ge[k] * Wf[k * DD + d];
    fc[b * DD + d] = o;
}

// ---- precompute: WkT[k][d] = W_node[d][k] (k<128);  W_og = W_out @ Wl^T ----
__global__ __launch_bounds__(128)
void precompute_w(const float* __restrict__ Wn, const float* __restrict__ Wout,
                  float* __restrict__ Wog, float* __restrict__ WkT) {
    int k = blockIdx.x, d = threadIdx.x;
    WkT[k * DD + d] = Wn[d * 384 + k];
    float s = 0.f;
    for (int e = 0; e < DD; ++e) s += Wout[k * DD + e] * Wn[d * 384 + 256 + e];
    Wog[k * DD + d] = s;
}

// ---------------------------- main decoder ----------------------------------
// v15 = r12's math (EA E-lo LDS cache kept; r13 proved L3 doesn't replace it)
// at 1024 threads / 16 waves. Grid==256==CUs pins 1 block/CU, so the ONLY
// occupancy lever is waves/block: 8 -> 16. VGPR budget 65536/1024 = 64;
// every phase's live set kept <= ~50 named scalars. Trajectory-feeding
// reductions bit-identical to r12 (e-bar slot/round decomposition identical;
// phase0/qt/hc/gs/stats verbatim under tid<512); compat/logits use the
// r6/r10-proven half-row shfl(1) split. Pt stride 8 -> 12 (aligned float4,
// write conflicts 16-way -> floor).
struct SMw15 {
    float EA[NN * 64];    // 131072 B  E-lo, row n quad q at (q^(n&15))
    float Pt[NN * 12];    // 24576 B   P[n][12]; aliases: slots[4][8][128]@0,
                          //           part[4][128]@0, lgp[512]@4096
    float qt[HH * DD];    // 4096 B    q~; alias eb[8][128] after compat
    float qarr[DD];
    float fcs[DD];
    float hcv[DD];
    float gs[DD];
    float curE[DD];
    float l[HH];
    float Mh[HH];
    float redf[16];
    float stat[2];
    unsigned char visf[NN];
    int   cur;
    float rbv;
};

__global__ __launch_bounds__(1024)
void decoder(const float* __restrict__ E, const float* __restrict__ Ws,
             const float* __restrict__ Wn, const float* __restrict__ fc,
             const float* __restrict__ Wog, const float* __restrict__ WkT,
             float* __restrict__ out_logp, float* __restrict__ out_seq, int T) {
    __shared__ SMw15 sm;
    const int b = blockIdx.x, tid = threadIdx.x;
    const int lane = tid & 63, wv = tid >> 6;      // 16 waves
    const float* Eg = E + (size_t)b * NN * DD;
    const float4* Ef4 = (const float4*)Eg;

    float* const slots = &sm.Pt[0];            // [4][8][128] after P dies
    float* const part  = &sm.Pt[0];            // [4][128] small-phase partials
    float* const lgp   = &sm.Pt[4096];         // [512] logits
    float* const ebp   = &sm.qt[0];            // eb[8][128] after qt dies

    // ---- init: EA (E-lo swizzled, coalesced), fcs, curE(row0), visf, rbv ----
    #pragma unroll
    for (int i = 0; i < 8; ++i) {
        int f = i * 1024 + tid;
        int nn = f >> 4, cq = f & 15;
        *(float4*)&sm.EA[nn * 64 + ((cq ^ (nn & 15)) << 2)] = Ef4[nn * 32 + cq];
    }
    if (tid < DD) {
        sm.fcs[tid] = fc[b * DD + tid];
        sm.curE[tid] = Eg[tid];
    }
    if (tid < NN) sm.visf[tid] = 0;
    if (tid == 0) sm.cur = 0;
    if (tid < NN) {
        float s = 0.f;
        #pragma unroll 8
        for (int i = 0; i < 32; ++i) { float4 v = Ef4[tid * 32 + i]; s += dot4(v, v); }
        for (int o = 1; o < 64; o <<= 1) s = fmaxf(s, __shfl_xor(s, o));
        if (lane == 0) sm.redf[wv] = s;
    }
    __syncthreads();
    if (tid == 0) {
        float m = sm.redf[0];
        for (int i = 1; i < 8; ++i) m = fmaxf(m, sm.redf[i]);
        sm.rbv = sqrtf(m);
    }
    __syncthreads();

    for (int t = 0; t < T; ++t) {
        // ---- phase 0: q = fc + E[cur]@Ws + frac*Ws_last (r12 verbatim, tid<512) ----
        if (tid < 512) {
            const int g4 = tid >> 7, d128 = tid & 127;
            float s = 0.f;
            const float* Wsg = Ws + d128;
            int k0 = g4 * 32;
            #pragma unroll 8
            for (int k = k0; k < k0 + 32; ++k) s += sm.curE[k] * Wsg[k * DD];
            if (g4 == 3) s += ((float)t / (float)T) * Wsg[DD * DD];
            part[g4 * 128 + d128] = s;
        }
        __syncthreads();                                               // B1
        if (tid < DD)
            sm.qarr[tid] = sm.fcs[tid] + part[0 * 128 + tid] + part[1 * 128 + tid]
                         + part[2 * 128 + tid] + part[3 * 128 + tid];
        __syncthreads();                                               // B2
        // ---- qt (0.25 folded) + Cauchy-Schwarz norms (r12 verbatim, tid<512) ----
        if (tid < 512) {
            const int g4 = tid >> 7, d128 = tid & 127;
            const int hA = g4, hB = g4 + 4;
            const float* WA = WkT + (hA * 16) * DD + d128;
            const float* WB = WkT + (hB * 16) * DD + d128;
            float a = 0.f, c = 0.f;
            #pragma unroll
            for (int j = 0; j < 16; ++j) {
                a += sm.qarr[hA * 16 + j] * WA[j * DD];
                c += sm.qarr[hB * 16 + j] * WB[j * DD];
            }
            a *= 0.25f; c *= 0.25f;
            sm.qt[hA * DD + d128] = a;
            sm.qt[hB * DD + d128] = c;
            float sa = a * a, sc = c * c;
            for (int o = 1; o < 64; o <<= 1) {
                sa += __shfl_xor(sa, o);
                sc += __shfl_xor(sc, o);
            }
            if (lane == 0) { sm.redf[wv] = sa; sm.redf[8 + wv] = sc; }
        }
        __syncthreads();                                               // B3
        if (tid < 8) {
            int h = tid;
            float ss = (h < 4) ? (sm.redf[2 * h] + sm.redf[2 * h + 1])
                               : (sm.redf[8 + 2 * (h - 4)] + sm.redf[8 + 2 * (h - 4) + 1]);
            sm.Mh[h] = sqrtf(ss) * sm.rbv;
        }
        __syncthreads();                                               // B4

        // ---- compat: half-row per thread (n2,hf), shfl(1) combine (r6/r10 assoc) ----
        {
            const int n2 = tid >> 1, hf = tid & 1;
            float a0 = 0.f, a1 = 0.f, a2 = 0.f, a3 = 0.f,
                  a4 = 0.f, a5 = 0.f, a6 = 0.f, a7 = 0.f;
            if (hf == 0) {
                const int nm = n2 & 15;
                #pragma unroll 4
                for (int q = 0; q < 16; ++q) {
                    float4 ev = *(const float4*)&sm.EA[n2 * 64 + ((q ^ nm) << 2)];
                    const int qb = q * 4;
                    a0 += dot4(*(const float4*)&sm.qt[0 * DD + qb], ev);
                    a1 += dot4(*(const float4*)&sm.qt[1 * DD + qb], ev);
                    a2 += dot4(*(const float4*)&sm.qt[2 * DD + qb], ev);
                    a3 += dot4(*(const float4*)&sm.qt[3 * DD + qb], ev);
                    a4 += dot4(*(const float4*)&sm.qt[4 * DD + qb], ev);
                    a5 += dot4(*(const float4*)&sm.qt[5 * DD + qb], ev);
                    a6 += dot4(*(const float4*)&sm.qt[6 * DD + qb], ev);
                    a7 += dot4(*(const float4*)&sm.qt[7 * DD + qb], ev);
                }
            } else {
                #pragma unroll 4
                for (int q = 0; q < 16; ++q) {
                    float4 ev = Ef4[n2 * 32 + 16 + q];
                    const int qb = 64 + q * 4;
                    a0 += dot4(*(const float4*)&sm.qt[0 * DD + qb], ev);
                    a1 += dot4(*(const float4*)&sm.qt[1 * DD + qb], ev);
                    a2 += dot4(*(const float4*)&sm.qt[2 * DD + qb], ev);
                    a3 += dot4(*(const float4*)&sm.qt[3 * DD + qb], ev);
                    a4 += dot4(*(const float4*)&sm.qt[4 * DD + qb], ev);
                    a5 += dot4(*(const float4*)&sm.qt[5 * DD + qb], ev);
                    a6 += dot4(*(const float4*)&sm.qt[6 * DD + qb], ev);
                    a7 += dot4(*(const float4*)&sm.qt[7 * DD + qb], ev);
                }
            }
            a0 += __shfl_xor(a0, 1); a1 += __shfl_xor(a1, 1);
            a2 += __shfl_xor(a2, 1); a3 += __shfl_xor(a3, 1);
            a4 += __shfl_xor(a4, 1); a5 += __shfl_xor(a5, 1);
            a6 += __shfl_xor(a6, 1); a7 += __shfl_xor(a7, 1);
            if (hf == 0) {
                const bool vn = (sm.visf[n2] != 0);
                float4 Pa, Pb;
                Pa.x = vn ? 0.f : expf(a0 - sm.Mh[0]);
                Pa.y = vn ? 0.f : expf(a1 - sm.Mh[1]);
                Pa.z = vn ? 0.f : expf(a2 - sm.Mh[2]);
                Pa.w = vn ? 0.f : expf(a3 - sm.Mh[3]);
                Pb.x = vn ? 0.f : expf(a4 - sm.Mh[4]);
                Pb.y = vn ? 0.f : expf(a5 - sm.Mh[5]);
                Pb.z = vn ? 0.f : expf(a6 - sm.Mh[6]);
                Pb.w = vn ? 0.f : expf(a7 - sm.Mh[7]);
                *(float4*)&sm.Pt[n2 * 12]     = Pa;
                *(float4*)&sm.Pt[n2 * 12 + 4] = Pb;
            }
        }
        __syncthreads();                                               // B5

        // ---- l[h] (waves 0-7, r12 order) ----
        if (wv < 8) {
            const int h = wv;
            float sl = 0.f;
            #pragma unroll
            for (int i = 0; i < 8; ++i) sl += sm.Pt[(lane + i * 64) * 12 + h];
            for (int o = 1; o < 64; o <<= 1) sl += __shfl_xor(sl, o);
            if (lane == 0) sm.l[h] = sl;
        }
        // ---- e-bar: wave = 32-row chunk (ch=wv), lane = (hg,dq); 4 heads/thread ----
        {
            const int ch = wv, dq = lane & 31, hg = lane >> 5;
            const int r0 = ch * 32;
            float4 a0 = {0,0,0,0}, a1 = {0,0,0,0}, a2 = {0,0,0,0}, a3 = {0,0,0,0};
            #pragma unroll 2
            for (int i = 0; i < 32; ++i) {
                const int r = r0 + i;
                float4 ev = (dq < 16)
                    ? *(const float4*)&sm.EA[r * 64 + ((dq ^ (r & 15)) << 2)]
                    : Ef4[r * 32 + dq];
                float4 p = (hg == 0) ? *(const float4*)&sm.Pt[r * 12]
                                     : *(const float4*)&sm.Pt[r * 12 + 4];
                fma4(a0, p.x, ev); fma4(a1, p.y, ev);
                fma4(a2, p.z, ev); fma4(a3, p.w, ev);
            }
            __syncthreads();                      // B6: P (and l) reads done
            // staged combine: slot = ch&3, rnd = ch>>2 (identical to r12)
            const int slot = ch & 3, rnd = ch >> 2;
            #pragma unroll
            for (int rr = 0; rr < 4; ++rr) {
                if (rnd == rr) {
                    float* sp = slots + (size_t)slot * 1024 + (size_t)hg * 512 + dq * 4;
                    if (rr == 0) {
                        *(float4*)&sp[0 * 128] = a0; *(float4*)&sp[1 * 128] = a1;
                        *(float4*)&sp[2 * 128] = a2; *(float4*)&sp[3 * 128] = a3;
                    } else {
#define STA(j_, av_) { float4 tv = *(float4*)&sp[j_ * 128];                      \
                        tv.x += av_.x; tv.y += av_.y; tv.z += av_.z; tv.w += av_.w; \
                        *(float4*)&sp[j_ * 128] = tv; }
                        STA(0, a0) STA(1, a1) STA(2, a2) STA(3, a3)
#undef STA
                    }
                }
                __syncthreads();                                       // B7-B10
            }
        }
        {   // combine 4 slots -> eb[h][d] normalized (1024 threads, one each)
            const int h = tid >> 7, d = tid & 127;
            float a = slots[0 * 1024 + h * 128 + d] + slots[1 * 1024 + h * 128 + d]
                    + slots[2 * 1024 + h * 128 + d] + slots[3 * 1024 + h * 128 + d];
            ebp[h * 128 + d] = a * (1.0f / sm.l[h]);
        }
        __syncthreads();                                               // B11

        // ---- hc = eb @ Wv (r12 verbatim, tid<512) ----
        if (tid < 512) {
            const int g4 = tid >> 7, d128 = tid & 127;
            float s = 0.f;
            int k0 = g4 * 32;
            const int hh = d128 >> 4;
            const float* Wv = Wn + 128 + d128;
            #pragma unroll 8
            for (int d = k0; d < k0 + 32; ++d) s += ebp[hh * 128 + d] * Wv[d * 384];
            part[g4 * 128 + d128] = s;
        }
        __syncthreads();                                               // B12
        if (tid < DD)
            sm.hcv[tid] = part[0 * 128 + tid] + part[1 * 128 + tid]
                        + part[2 * 128 + tid] + part[3 * 128 + tid];
        __syncthreads();                                               // B13
        // ---- g~ = (hc @ Wog) * inv_sqrt_D (r12 verbatim, tid<512) ----
        if (tid < 512) {
            const int g4 = tid >> 7, d128 = tid & 127;
            float s = 0.f;
            int k0 = g4 * 32;
            #pragma unroll 8
            for (int k = k0; k < k0 + 32; ++k) s += sm.hcv[k] * Wog[k * DD + d128];
            part[g4 * 128 + d128] = s;
        }
        __syncthreads();                                               // B14
        if (tid < DD)
            sm.gs[tid] = (part[0 * 128 + tid] + part[1 * 128 + tid]
                        + part[2 * 128 + tid] + part[3 * 128 + tid]) * INV_SQRT_D;
        __syncthreads();                                               // B15

        // ---- logits: half-row per thread, shfl(1) (r10 assoc; EA for lo) ----
        {
            const int n2 = tid >> 1, hf = tid & 1;
            float s = 0.f;
            if (hf == 0) {
                const int nm = n2 & 15;
                #pragma unroll 4
                for (int q = 0; q < 16; ++q) {
                    float4 ev = *(const float4*)&sm.EA[n2 * 64 + ((q ^ nm) << 2)];
                    s += dot4(*(const float4*)&sm.gs[q * 4], ev);
                }
            } else {
                #pragma unroll 4
                for (int q = 0; q < 16; ++q) {
                    float4 ev = Ef4[n2 * 32 + 16 + q];
                    s += dot4(*(const float4*)&sm.gs[64 + q * 4], ev);
                }
            }
            s += __shfl_xor(s, 1);
            if (hf == 0) lgp[n2] = sm.visf[n2] ? NEGC : 10.0f * tanhf(s);
        }
        __syncthreads();                                               // B16

        // ---- stats + argmax in wave 0 (r12 verbatim) ----
        if (wv == 0) {
            float x0 = lgp[lane],       x1 = lgp[lane + 64],
                  x2 = lgp[lane + 128], x3 = lgp[lane + 192],
                  x4 = lgp[lane + 256], x5 = lgp[lane + 320],
                  x6 = lgp[lane + 384], x7 = lgp[lane + 448];
            float m = fmaxf(fmaxf(fmaxf(x0, x1), fmaxf(x2, x3)),
                            fmaxf(fmaxf(x4, x5), fmaxf(x6, x7)));
            for (int o = 1; o < 64; o <<= 1) m = fmaxf(m, __shfl_xor(m, o));
            float ssum = expf(x0 - m) + expf(x1 - m) + expf(x2 - m) + expf(x3 - m)
                       + expf(x4 - m) + expf(x5 - m) + expf(x6 - m) + expf(x7 - m);
            for (int o = 1; o < 64; o <<= 1) ssum += __shfl_xor(ssum, o);
            float lse = logf(ssum);
            float bv = (x0 - m) - lse; int bi = lane;
#define AMX(xi, ii) { float v_ = ((xi) - m) - lse; int i_ = (ii);           \
            if (v_ > bv) { bv = v_; bi = i_; } }
            AMX(x1, lane + 64)  AMX(x2, lane + 128) AMX(x3, lane + 192)
            AMX(x4, lane + 256) AMX(x5, lane + 320) AMX(x6, lane + 384)
            AMX(x7, lane + 448)
#undef AMX
            for (int o = 1; o < 64; o <<= 1) {
                float ov = __shfl_xor(bv, o);
                int   oi = __shfl_xor(bi, o);
                if (ov > bv || (ov == bv && oi < bi)) { bv = ov; bi = oi; }
            }
            if (lane == 0) {
                sm.stat[0] = m;
                sm.stat[1] = lse;
                sm.cur = bi;
                out_seq[(size_t)b * T + t] = (float)bi;
            }
        }
        __syncthreads();                                               // B17
        // ---- store log_p; update visited + curE ----
        if (tid < NN) {
            float lp = (lgp[tid] - sm.stat[0]) - sm.stat[1];
            out_logp[((size_t)b * T + t) * NN + tid] = lp;
            const int cu = sm.cur;
            if (tid == cu) sm.visf[tid] = 1;
            if (tid < DD) {
                float vv;
                if (tid < 64)
                    vv = sm.EA[cu * 64 + ((((tid >> 2) ^ (cu & 15))) << 2) + (tid & 3)];
                else
                    vv = Eg[cu * DD + tid];
                sm.curE[tid] = vv;
            }
        }
        __syncthreads();                                               // B18
    }
}

// ------------------------------- launcher -----------------------------------
extern "C" void kernel_launch(void* const* d_in, const int* in_sizes, int n_in,
                              void* d_out, int out_size, void* d_ws, size_t ws_size,
                              hipStream_t stream) {
    const float* E    = (const float*)d_in[0];   // [B,N,D]
    const float* Wn   = (const float*)d_in[1];   // [D,3D]
    const float* Wf   = (const float*)d_in[2];   // [D,D]
    const float* Ws   = (const float*)d_in[3];   // [D+1,D]
    const float* Wout = (const float*)d_in[4];   // [D,D]
    float* out = (float*)d_out;

    const int T = out_size / (BB * (NN + 1));    // = num_steps (64)

    float* fcp = (float*)d_ws;                   // [B,D]
    float* Wog = fcp + BB * DD;                  // [128,128]
    float* WkT = Wog + DD * DD;                  // [128,128]

    precompute_fc<<<BB, 128, 0, stream>>>(E, Wf, fcp);
    precompute_w<<<DD, 128, 0, stream>>>(Wn, Wout, Wog, WkT);
    decoder<<<BB, 1024, 0, stream>>>(E, Ws, Wn, fcp, Wog, WkT,
                                     out, out + (size_t)BB * T * NN, T);
}

// Round 15
// 2229.734 us; speedup vs baseline: 1.8527x; 1.8527x over previous
//
#include <hip/hip_runtime.h>

#define BB 256
#define NN 512
#define DD 128
#define HH 8

static constexpr float NEGC = -1e9f;
static constexpr float INV_SQRT_D = 0.08838834764831845f; // 1/sqrt(128)

__device__ __forceinline__ float dot4(float4 a, float4 b) {
    return a.x * b.x + a.y * b.y + a.z * b.z + a.w * b.w;
}
__device__ __forceinline__ void fma4(float4& a, float p, float4 e) {
    a.x += p * e.x; a.y += p * e.y; a.z += p * e.z; a.w += p * e.w;
}

// ---------------- precompute: fixed_ctx = mean_n(E) @ W_fixed ----------------
__global__ __launch_bounds__(128)
void precompute_fc(const float* __restrict__ E, const float* __restrict__ Wf,
                   float* __restrict__ fc) {
    int b = blockIdx.x, d = threadIdx.x;
    __shared__ float ge[DD];
    const float* Eb = E + (size_t)b * NN * DD;
    float s = 0.f;
    for (int n = 0; n < NN; ++n) s += Eb[n * DD + d];
    ge[d] = s * (1.0f / 512.0f);
    __syncthreads();
    float o = 0.f;
    for (int k = 0; k < DD; ++k) o += ge[k] * Wf[k * DD + d];
    fc[b * DD + d] = o;
}

// ---- precompute: WkT[k][d] = W_node[d][k] (k<128);  W_og = W_out @ Wl^T ----
__global__ __launch_bounds__(128)
void precompute_w(const float* __restrict__ Wn, const float* __restrict__ Wout,
                  float* __restrict__ Wog, float* __restrict__ WkT) {
    int k = blockIdx.x, d = threadIdx.x;
    WkT[k * DD + d] = Wn[d * 384 + k];
    float s = 0.f;
    for (int e = 0; e < DD; ++e) s += Wout[k * DD + e] * Wn[d * 384 + 256 + e];
    Wog[k * DD + d] = s;
}

// ---- precompute: Wvog[h][e][g] = sum_{j<16} Wv[e][16h+j] * Wog[16h+j][g] ----
// (Wv = Wn[:,128:256]).  Lets the decoder do gs = (sum_h eb_h @ Wvog_h)*scale
// directly, collapsing hc->hcv->g~->gs (4 barriers) into 2.
__global__ __launch_bounds__(128)
void precompute_w2(const float* __restrict__ Wn, const float* __restrict__ Wog,
                   float* __restrict__ Wvog) {
    int e = blockIdx.x, g = threadIdx.x;
    #pragma unroll
    for (int h = 0; h < 8; ++h) {
        float s = 0.f;
        #pragma unroll
        for (int j = 0; j < 16; ++j)
            s += Wn[e * 384 + 128 + 16 * h + j] * Wog[(16 * h + j) * 128 + g];
        Wvog[((size_t)h * 128 + e) * 128 + g] = s;
    }
}

// ---------------------------- main decoder ----------------------------------
// v16 = r12 (2055us champion) with:
//  1) Wvog fusion: B12-B15 (4 barriers) -> 2 barriers.
//  2) curE eliminated: phase0 reads E[cur] from global (wave-uniform addr ->
//     scalar loads; E is read-only so no coherence issue). B18 dropped: the
//     visf/cur writes in the store phase are ordered by B1 before any reader.
//  3) Pt stride 8 -> 12 (16B-aligned): compat P-writes 4->2-way bank
//     conflicts, l-pass 16->8-way (layout numerically validated in r14).
// Compat tiling, e-bar slot/round combine, stats/argmax: r12-verbatim.
// Barriers/step: 18 -> 15.
struct SMw16 {
    float EA[NN * 64];    // 131072 B  E-lo, row n quad q at (q^(n&15))
    float Pt[NN * 12];    // 24576 B   P[n][.]; aliases: slots[4][8][128]@0,
                          //           part[4][128]@0, lgp[512]@4096 floats
    float qt[HH * DD];    // 4096 B    q~; alias eb[8][128] after compat
    float qarr[DD];
    float fcs[DD];
    float gs[DD];
    float l[HH];
    float Mh[HH];
    float redf[16];
    float stat[2];
    unsigned char visf[NN];
    int   cur;
    float rbv;
};

__global__ __launch_bounds__(512)
void decoder(const float* __restrict__ E, const float* __restrict__ Ws,
             const float* __restrict__ Wn, const float* __restrict__ fc,
             const float* __restrict__ Wog, const float* __restrict__ WkT,
             const float* __restrict__ Wvog,
             float* __restrict__ out_logp, float* __restrict__ out_seq, int T) {
    __shared__ SMw16 sm;
    const int b = blockIdx.x, tid = threadIdx.x;
    const int lane = tid & 63, wv = tid >> 6;
    const int g4 = tid >> 7, d128 = tid & 127;
    const float* Eg = E + (size_t)b * NN * DD;
    const float4* Ef4 = (const float4*)Eg;

    float* const slots = &sm.Pt[0];            // [4][8][128] after P dies
    float* const part  = &sm.Pt[0];            // [4][128] small-phase partials
    float* const lgp   = &sm.Pt[4096];         // [512] logits
    float* const ebp   = &sm.qt[0];            // eb[8][128] after qt dies

    // ---- init: EA (E-lo swizzled, coalesced), fcs, visf, rbv ----
    #pragma unroll
    for (int i = 0; i < 16; ++i) {
        int f = i * 512 + tid;
        int nn = f >> 4, cq = f & 15;
        *(float4*)&sm.EA[nn * 64 + ((cq ^ (nn & 15)) << 2)] = Ef4[nn * 32 + cq];
    }
    if (tid < DD) sm.fcs[tid] = fc[b * DD + tid];
    sm.visf[tid] = 0;
    if (tid == 0) sm.cur = 0;
    {
        float s = 0.f;
        #pragma unroll 8
        for (int i = 0; i < 32; ++i) { float4 v = Ef4[tid * 32 + i]; s += dot4(v, v); }
        for (int o = 1; o < 64; o <<= 1) s = fmaxf(s, __shfl_xor(s, o));
        if (lane == 0) sm.redf[wv] = s;
    }
    __syncthreads();
    if (tid == 0) {
        float m = sm.redf[0];
        for (int i = 1; i < 8; ++i) m = fmaxf(m, sm.redf[i]);
        sm.rbv = sqrtf(m);
    }
    __syncthreads();

    for (int t = 0; t < T; ++t) {
        // ---- phase 0: q = fc + E[cur]@Ws + frac*Ws_last (E[cur] from global) ----
        {
            const int cu = sm.cur;
            const float* Ecur = Eg + (size_t)cu * DD;
            const float* Wsg = Ws + d128;
            float s = 0.f;
            int k0 = g4 * 32;
            #pragma unroll 8
            for (int k = k0; k < k0 + 32; ++k) s += Ecur[k] * Wsg[k * DD];
            if (g4 == 3) s += ((float)t / (float)T) * Wsg[DD * DD];
            part[g4 * 128 + d128] = s;
        }
        __syncthreads();                                               // B1
        if (tid < DD)
            sm.qarr[tid] = sm.fcs[tid] + part[0 * 128 + tid] + part[1 * 128 + tid]
                         + part[2 * 128 + tid] + part[3 * 128 + tid];
        __syncthreads();                                               // B2
        // ---- qt (0.25 folded) + Cauchy-Schwarz norms (r12 verbatim) ----
        {
            const int hA = g4, hB = g4 + 4;
            const float* WA = WkT + (hA * 16) * DD + d128;
            const float* WB = WkT + (hB * 16) * DD + d128;
            float a = 0.f, c = 0.f;
            #pragma unroll
            for (int j = 0; j < 16; ++j) {
                a += sm.qarr[hA * 16 + j] * WA[j * DD];
                c += sm.qarr[hB * 16 + j] * WB[j * DD];
            }
            a *= 0.25f; c *= 0.25f;
            sm.qt[hA * DD + d128] = a;
            sm.qt[hB * DD + d128] = c;
            float sa = a * a, sc = c * c;
            for (int o = 1; o < 64; o <<= 1) {
                sa += __shfl_xor(sa, o);
                sc += __shfl_xor(sc, o);
            }
            if (lane == 0) { sm.redf[wv] = sa; sm.redf[8 + wv] = sc; }
        }
        __syncthreads();                                               // B3
        if (tid < 8) {
            int h = tid;
            float ss = (h < 4) ? (sm.redf[2 * h] + sm.redf[2 * h + 1])
                               : (sm.redf[8 + 2 * (h - 4)] + sm.redf[8 + 2 * (h - 4) + 1]);
            sm.Mh[h] = sqrtf(ss) * sm.rbv;
        }
        __syncthreads();                                               // B4

        // ---- compat: 2 rows/thread (tid<256), r12 verbatim; Pt stride 12 ----
        if (tid < 256) {
            const int n0 = tid, n1 = tid + 256;
            const int m0 = n0 & 15, m1 = n1 & 15;
            float b0 = 0.f, b1 = 0.f, b2 = 0.f, b3 = 0.f,
                  b4 = 0.f, b5 = 0.f, b6 = 0.f, b7 = 0.f;
            float c0 = 0.f, c1 = 0.f, c2 = 0.f, c3 = 0.f,
                  c4 = 0.f, c5 = 0.f, c6 = 0.f, c7 = 0.f;
            #pragma unroll 4
            for (int qd = 0; qd < 16; ++qd) {      // lo half from LDS
                float4 e0 = *(const float4*)&sm.EA[n0 * 64 + ((qd ^ m0) << 2)];
                float4 e1 = *(const float4*)&sm.EA[n1 * 64 + ((qd ^ m1) << 2)];
#define CH(h_, bb_, cc_) { float4 qv = *(const float4*)&sm.qt[h_ * DD + qd * 4]; \
                bb_ += dot4(qv, e0); cc_ += dot4(qv, e1); }
                CH(0, b0, c0) CH(1, b1, c1) CH(2, b2, c2) CH(3, b3, c3)
                CH(4, b4, c4) CH(5, b5, c5) CH(6, b6, c6) CH(7, b7, c7)
#undef CH
            }
            #pragma unroll 4
            for (int qd = 0; qd < 16; ++qd) {      // hi half from global
                float4 e0 = Ef4[n0 * 32 + 16 + qd];
                float4 e1 = Ef4[n1 * 32 + 16 + qd];
#define CH(h_, bb_, cc_) { float4 qv = *(const float4*)&sm.qt[h_ * DD + 64 + qd * 4]; \
                bb_ += dot4(qv, e0); cc_ += dot4(qv, e1); }
                CH(0, b0, c0) CH(1, b1, c1) CH(2, b2, c2) CH(3, b3, c3)
                CH(4, b4, c4) CH(5, b5, c5) CH(6, b6, c6) CH(7, b7, c7)
#undef CH
            }
            const bool v0 = (sm.visf[n0] != 0), v1 = (sm.visf[n1] != 0);
            float4 P0a, P0b, P1a, P1b;
            P0a.x = v0 ? 0.f : expf(b0 - sm.Mh[0]);
            P0a.y = v0 ? 0.f : expf(b1 - sm.Mh[1]);
            P0a.z = v0 ? 0.f : expf(b2 - sm.Mh[2]);
            P0a.w = v0 ? 0.f : expf(b3 - sm.Mh[3]);
            P0b.x = v0 ? 0.f : expf(b4 - sm.Mh[4]);
            P0b.y = v0 ? 0.f : expf(b5 - sm.Mh[5]);
            P0b.z = v0 ? 0.f : expf(b6 - sm.Mh[6]);
            P0b.w = v0 ? 0.f : expf(b7 - sm.Mh[7]);
            P1a.x = v1 ? 0.f : expf(c0 - sm.Mh[0]);
            P1a.y = v1 ? 0.f : expf(c1 - sm.Mh[1]);
            P1a.z = v1 ? 0.f : expf(c2 - sm.Mh[2]);
            P1a.w = v1 ? 0.f : expf(c3 - sm.Mh[3]);
            P1b.x = v1 ? 0.f : expf(c4 - sm.Mh[4]);
            P1b.y = v1 ? 0.f : expf(c5 - sm.Mh[5]);
            P1b.z = v1 ? 0.f : expf(c6 - sm.Mh[6]);
            P1b.w = v1 ? 0.f : expf(c7 - sm.Mh[7]);
            *(float4*)&sm.Pt[n0 * 12]     = P0a;
            *(float4*)&sm.Pt[n0 * 12 + 4] = P0b;
            *(float4*)&sm.Pt[n1 * 12]     = P1a;
            *(float4*)&sm.Pt[n1 * 12 + 4] = P1b;
        }
        __syncthreads();                                               // B5

        // ---- l[h] (wave h) + e-bar accumulate (r12 verbatim, stride 12) ----
        {
            const int h = wv;
            float sl = 0.f;
            #pragma unroll
            for (int i = 0; i < 8; ++i) sl += sm.Pt[(lane + i * 64) * 12 + h];
            for (int o = 1; o < 64; o <<= 1) sl += __shfl_xor(sl, o);
            if (lane == 0) sm.l[h] = sl;
        }
        const int dq = tid & 31, ch = tid >> 5;    // d-quad, 32-row chunk
        float4 a0 = {0,0,0,0}, a1 = {0,0,0,0}, a2 = {0,0,0,0}, a3 = {0,0,0,0},
               a4 = {0,0,0,0}, a5 = {0,0,0,0}, a6 = {0,0,0,0}, a7 = {0,0,0,0};
        {
            const int r0 = ch * 32;
            #pragma unroll 2
            for (int i = 0; i < 32; ++i) {
                const int r = r0 + i;
                float4 ev = (dq < 16)
                    ? *(const float4*)&sm.EA[r * 64 + ((dq ^ (r & 15)) << 2)]
                    : Ef4[r * 32 + dq];
                float4 pA = *(const float4*)&sm.Pt[r * 12];
                float4 pB = *(const float4*)&sm.Pt[r * 12 + 4];
                fma4(a0, pA.x, ev); fma4(a1, pA.y, ev);
                fma4(a2, pA.z, ev); fma4(a3, pA.w, ev);
                fma4(a4, pB.x, ev); fma4(a5, pB.y, ev);
                fma4(a6, pB.z, ev); fma4(a7, pB.w, ev);
            }
        }
        __syncthreads();                          // B6: P dead, slots alias ok
        {   // staged partial combine: 4 rounds into 4 slots (slot = ch&3)
            const int slot = ch & 3, rnd = ch >> 2;
            #pragma unroll
            for (int rr = 0; rr < 4; ++rr) {
                if (rnd == rr) {
                    float* sp = slots + (size_t)slot * 1024 + dq * 4;
                    if (rr == 0) {
#define STW(h_, av_) *(float4*)&sp[h_ * 128] = av_;
                        STW(0, a0) STW(1, a1) STW(2, a2) STW(3, a3)
                        STW(4, a4) STW(5, a5) STW(6, a6) STW(7, a7)
#undef STW
                    } else {
#define STA(h_, av_) { float4 tv = *(float4*)&sp[h_ * 128];                  \
                        tv.x += av_.x; tv.y += av_.y; tv.z += av_.z; tv.w += av_.w; \
                        *(float4*)&sp[h_ * 128] = tv; }
                        STA(0, a0) STA(1, a1) STA(2, a2) STA(3, a3)
                        STA(4, a4) STA(5, a5) STA(6, a6) STA(7, a7)
#undef STA
                    }
                }
                __syncthreads();                                       // B7-B10
            }
        }
        {   // combine 4 slots -> eb[h][d] normalized (eb aliases qt)
            const int h = tid >> 6, d2 = (tid & 63) * 2;
            float inv = 1.0f / sm.l[h];
            #pragma unroll
            for (int r = 0; r < 2; ++r) {
                int d = d2 + r;
                float a = slots[0 * 1024 + h * 128 + d] + slots[1 * 1024 + h * 128 + d]
                        + slots[2 * 1024 + h * 128 + d] + slots[3 * 1024 + h * 128 + d];
                ebp[h * 128 + d] = a * inv;
            }
        }
        __syncthreads();                                               // B11

        // ---- gs partials via Wvog: thread (g4,d128) over heads 2g4, 2g4+1 ----
        {
            const int h0 = g4 * 2;
            const float* W0 = Wvog + ((size_t)h0 * 128) * 128 + d128;
            const float* W1 = W0 + 128 * 128;
            float s = 0.f;
            #pragma unroll 4
            for (int eq = 0; eq < 32; ++eq) {
                float4 e0 = *(const float4*)&ebp[h0 * 128 + eq * 4];
                s += e0.x * W0[(eq * 4 + 0) * 128] + e0.y * W0[(eq * 4 + 1) * 128]
                   + e0.z * W0[(eq * 4 + 2) * 128] + e0.w * W0[(eq * 4 + 3) * 128];
            }
            #pragma unroll 4
            for (int eq = 0; eq < 32; ++eq) {
                float4 e1 = *(const float4*)&ebp[(h0 + 1) * 128 + eq * 4];
                s += e1.x * W1[(eq * 4 + 0) * 128] + e1.y * W1[(eq * 4 + 1) * 128]
                   + e1.z * W1[(eq * 4 + 2) * 128] + e1.w * W1[(eq * 4 + 3) * 128];
            }
            part[g4 * 128 + d128] = s;
        }
        __syncthreads();                                               // B12
        if (tid < DD)
            sm.gs[tid] = (part[0 * 128 + tid] + part[1 * 128 + tid]
                        + part[2 * 128 + tid] + part[3 * 128 + tid]) * INV_SQRT_D;
        __syncthreads();                                               // B13

        // ---- logits: thread n = g~ . E[n] (lo LDS, hi global; r12 verbatim) ----
        {
            const int n = tid, nm = n & 15;
            float s = 0.f;
            #pragma unroll 4
            for (int qd = 0; qd < 16; ++qd) {
                float4 gq = *(const float4*)&sm.gs[qd * 4];
                float4 ev = *(const float4*)&sm.EA[n * 64 + ((qd ^ nm) << 2)];
                s += dot4(gq, ev);
            }
            #pragma unroll 4
            for (int qd = 0; qd < 16; ++qd) {
                float4 gq = *(const float4*)&sm.gs[64 + qd * 4];
                float4 ev = Ef4[n * 32 + 16 + qd];
                s += dot4(gq, ev);
            }
            lgp[n] = sm.visf[n] ? NEGC : 10.0f * tanhf(s);
        }
        __syncthreads();                                               // B14

        // ---- stats + argmax in wave 0 (r12 verbatim) ----
        if (wv == 0) {
            float x0 = lgp[lane],       x1 = lgp[lane + 64],
                  x2 = lgp[lane + 128], x3 = lgp[lane + 192],
                  x4 = lgp[lane + 256], x5 = lgp[lane + 320],
                  x6 = lgp[lane + 384], x7 = lgp[lane + 448];
            float m = fmaxf(fmaxf(fmaxf(x0, x1), fmaxf(x2, x3)),
                            fmaxf(fmaxf(x4, x5), fmaxf(x6, x7)));
            for (int o = 1; o < 64; o <<= 1) m = fmaxf(m, __shfl_xor(m, o));
            float ssum = expf(x0 - m) + expf(x1 - m) + expf(x2 - m) + expf(x3 - m)
                       + expf(x4 - m) + expf(x5 - m) + expf(x6 - m) + expf(x7 - m);
            for (int o = 1; o < 64; o <<= 1) ssum += __shfl_xor(ssum, o);
            float lse = logf(ssum);
            float bv = (x0 - m) - lse; int bi = lane;
#define AMX(xi, ii) { float v_ = ((xi) - m) - lse; int i_ = (ii);           \
            if (v_ > bv) { bv = v_; bi = i_; } }
            AMX(x1, lane + 64)  AMX(x2, lane + 128) AMX(x3, lane + 192)
            AMX(x4, lane + 256) AMX(x5, lane + 320) AMX(x6, lane + 384)
            AMX(x7, lane + 448)
#undef AMX
            for (int o = 1; o < 64; o <<= 1) {
                float ov = __shfl_xor(bv, o);
                int   oi = __shfl_xor(bi, o);
                if (ov > bv || (ov == bv && oi < bi)) { bv = ov; bi = oi; }
            }
            if (lane == 0) {
                sm.stat[0] = m;
                sm.stat[1] = lse;
                sm.cur = bi;
                out_seq[(size_t)b * T + t] = (float)bi;
            }
        }
        __syncthreads();                                               // B15
        // ---- store log_p; update visited. (No B18: next reader of visf/cur
        //      is after B1; lgp region is disjoint from part.) ----
        {
            float lp = (lgp[tid] - sm.stat[0]) - sm.stat[1];
            out_logp[((size_t)b * T + t) * NN + tid] = lp;
            if (tid == sm.cur) sm.visf[tid] = 1;
        }
    }
}

// ------------------------------- launcher -----------------------------------
extern "C" void kernel_launch(void* const* d_in, const int* in_sizes, int n_in,
                              void* d_out, int out_size, void* d_ws, size_t ws_size,
                              hipStream_t stream) {
    const float* E    = (const float*)d_in[0];   // [B,N,D]
    const float* Wn   = (const float*)d_in[1];   // [D,3D]
    const float* Wf   = (const float*)d_in[2];   // [D,D]
    const float* Ws   = (const float*)d_in[3];   // [D+1,D]
    const float* Wout = (const float*)d_in[4];   // [D,D]
    float* out = (float*)d_out;

    const int T = out_size / (BB * (NN + 1));    // = num_steps (64)

    float* fcp  = (float*)d_ws;                  // [B,D]      32768 f
    float* Wog  = fcp + BB * DD;                 // [128,128]  16384 f
    float* WkT  = Wog + DD * DD;                 // [128,128]  16384 f
    float* Wvog = WkT + DD * DD;                 // [8,128,128] 131072 f

    precompute_fc<<<BB, 128, 0, stream>>>(E, Wf, fcp);
    precompute_w<<<DD, 128, 0, stream>>>(Wn, Wout, Wog, WkT);
    precompute_w2<<<DD, 128, 0, stream>>>(Wn, Wog, Wvog);
    decoder<<<BB, 512, 0, stream>>>(E, Ws, Wn, fcp, Wog, WkT, Wvog,
                                    out, out + (size_t)BB * T * NN, T);
}

// Round 16
// 2212.146 us; speedup vs baseline: 1.8675x; 1.0080x over previous
//
#include <hip/hip_runtime.h>

#define BB 256
#define NN 512
#define DD 128
#define HH 8

static constexpr float NEGC = -1e9f;
static constexpr float INV_SQRT_D = 0.08838834764831845f; // 1/sqrt(128)

__device__ __forceinline__ float dot4(float4 a, float4 b) {
    return a.x * b.x + a.y * b.y + a.z * b.z + a.w * b.w;
}
__device__ __forceinline__ void fma4(float4& a, float p, float4 e) {
    a.x += p * e.x; a.y += p * e.y; a.z += p * e.z; a.w += p * e.w;
}

// ---------------- precompute: fixed_ctx = mean_n(E) @ W_fixed ----------------
__global__ __launch_bounds__(128)
void precompute_fc(const float* __restrict__ E, const float* __restrict__ Wf,
                   float* __restrict__ fc) {
    int b = blockIdx.x, d = threadIdx.x;
    __shared__ float ge[DD];
    const float* Eb = E + (size_t)b * NN * DD;
    float s = 0.f;
    for (int n = 0; n < NN; ++n) s += Eb[n * DD + d];
    ge[d] = s * (1.0f / 512.0f);
    __syncthreads();
    float o = 0.f;
    for (int k = 0; k < DD; ++k) o += ge[k] * Wf[k * DD + d];
    fc[b * DD + d] = o;
}

// ---- precompute: WkT[k][d] = W_node[d][k] (k<128);  W_og = W_out @ Wl^T ----
__global__ __launch_bounds__(128)
void precompute_w(const float* __restrict__ Wn, const float* __restrict__ Wout,
                  float* __restrict__ Wog, float* __restrict__ WkT) {
    int k = blockIdx.x, d = threadIdx.x;
    WkT[k * DD + d] = Wn[d * 384 + k];
    float s = 0.f;
    for (int e = 0; e < DD; ++e) s += Wout[k * DD + e] * Wn[d * 384 + 256 + e];
    Wog[k * DD + d] = s;
}

// ---------------------------- main decoder ----------------------------------
// v17 = r12 (2055us champion) with 6 barriers + 6 serial mini-phases removed,
// every f32 value BIT-IDENTICAL to r12:
//  - qarr/Mh/hc/gs combine phases inlined into consumers via wave-uniform LDS
//    broadcasts (combine order (((fcs+p0)+p1)+p2)+p3 preserved exactly).
//  - softmax stats/argmax computed redundantly by ALL 8 waves (deterministic
//    -> identical results); `cur` lives in a register; stats->store barrier,
//    sm.cur and sm.stat round-trips eliminated.
//  - r15-validated: curE-elim (phase0 reads E[cur] global), Pt stride 12.
// Compat tiling, e-bar 4-round slot combine, logits, stats: r12-verbatim.
// Barriers/step: 18 -> 12.
struct SMw17 {
    float EA[NN * 64];    // 131072 B  E-lo, row n quad q at (q^(n&15))
    float Pt[NN * 12];    // 24576 B   P[n][.]; aliases: slots[4][8][128]@0,
                          //           part[4][128]@0, part2[4][128]@512,
                          //           lgp[512]@4096 floats
    float qt[HH * DD];    // 4096 B    q~; alias eb[8][128] after compat
    float fcs[DD];
    float redf[16];
    float l[HH];
    unsigned char visf[NN];
    float rbv;
};

__global__ __launch_bounds__(512)
void decoder(const float* __restrict__ E, const float* __restrict__ Ws,
             const float* __restrict__ Wn, const float* __restrict__ fc,
             const float* __restrict__ Wog, const float* __restrict__ WkT,
             float* __restrict__ out_logp, float* __restrict__ out_seq, int T) {
    __shared__ SMw17 sm;
    const int b = blockIdx.x, tid = threadIdx.x;
    const int lane = tid & 63, wv = tid >> 6;
    const int g4 = tid >> 7, d128 = tid & 127;
    const float* Eg = E + (size_t)b * NN * DD;
    const float4* Ef4 = (const float4*)Eg;

    float* const slots = &sm.Pt[0];            // [4][8][128] after P dies
    float* const part  = &sm.Pt[0];            // [4][128] phase0/hc partials
    float* const part2 = &sm.Pt[512];          // [4][128] g' partials
    float* const lgp   = &sm.Pt[4096];         // [512] logits
    float* const ebp   = &sm.qt[0];            // eb[8][128] after qt dies

    // ---- init: EA (E-lo swizzled, coalesced), fcs, visf, rbv ----
    #pragma unroll
    for (int i = 0; i < 16; ++i) {
        int f = i * 512 + tid;
        int nn = f >> 4, cq = f & 15;
        *(float4*)&sm.EA[nn * 64 + ((cq ^ (nn & 15)) << 2)] = Ef4[nn * 32 + cq];
    }
    if (tid < DD) sm.fcs[tid] = fc[b * DD + tid];
    sm.visf[tid] = 0;
    int cur = 0;                               // per-thread register, all agree
    {
        float s = 0.f;
        #pragma unroll 8
        for (int i = 0; i < 32; ++i) { float4 v = Ef4[tid * 32 + i]; s += dot4(v, v); }
        for (int o = 1; o < 64; o <<= 1) s = fmaxf(s, __shfl_xor(s, o));
        if (lane == 0) sm.redf[wv] = s;
    }
    __syncthreads();
    if (tid == 0) {
        float m = sm.redf[0];
        for (int i = 1; i < 8; ++i) m = fmaxf(m, sm.redf[i]);
        sm.rbv = sqrtf(m);
    }
    __syncthreads();

    for (int t = 0; t < T; ++t) {
        // ---- phase 0: q-partials = E[cur]@Ws (+ frac term); E[cur] global ----
        {
            const float* Ecur = Eg + (size_t)cur * DD;
            const float* Wsg = Ws + d128;
            float s = 0.f;
            int k0 = g4 * 32;
            #pragma unroll 8
            for (int k = k0; k < k0 + 32; ++k) s += Ecur[k] * Wsg[k * DD];
            if (g4 == 3) s += ((float)t / (float)T) * Wsg[DD * DD];
            part[g4 * 128 + d128] = s;
        }
        __syncthreads();                                               // B1
        // ---- qt (0.25 folded) + norms; q inlined via wave-uniform broadcasts ----
        {
            const int hA = g4, hB = g4 + 4;
            const float* WA = WkT + (hA * 16) * DD + d128;
            const float* WB = WkT + (hB * 16) * DD + d128;
            float a = 0.f, c = 0.f;
            #pragma unroll
            for (int j = 0; j < 16; ++j) {
                const int iA = hA * 16 + j, iB = hB * 16 + j;
                float qA = sm.fcs[iA] + part[0 * 128 + iA] + part[1 * 128 + iA]
                         + part[2 * 128 + iA] + part[3 * 128 + iA];
                float qB = sm.fcs[iB] + part[0 * 128 + iB] + part[1 * 128 + iB]
                         + part[2 * 128 + iB] + part[3 * 128 + iB];
                a += qA * WA[j * DD];
                c += qB * WB[j * DD];
            }
            a *= 0.25f; c *= 0.25f;
            sm.qt[hA * DD + d128] = a;
            sm.qt[hB * DD + d128] = c;
            float sa = a * a, sc = c * c;
            for (int o = 1; o < 64; o <<= 1) {
                sa += __shfl_xor(sa, o);
                sc += __shfl_xor(sc, o);
            }
            if (lane == 0) { sm.redf[wv] = sa; sm.redf[8 + wv] = sc; }
        }
        __syncthreads();                                               // B2
        // ---- compat: 2 rows/thread (tid<256), r12 verbatim; Mh inlined ----
        if (tid < 256) {
            const float rb = sm.rbv;
            float mh0 = sqrtf(sm.redf[0]  + sm.redf[1])  * rb;
            float mh1 = sqrtf(sm.redf[2]  + sm.redf[3])  * rb;
            float mh2 = sqrtf(sm.redf[4]  + sm.redf[5])  * rb;
            float mh3 = sqrtf(sm.redf[6]  + sm.redf[7])  * rb;
            float mh4 = sqrtf(sm.redf[8]  + sm.redf[9])  * rb;
            float mh5 = sqrtf(sm.redf[10] + sm.redf[11]) * rb;
            float mh6 = sqrtf(sm.redf[12] + sm.redf[13]) * rb;
            float mh7 = sqrtf(sm.redf[14] + sm.redf[15]) * rb;
            const int n0 = tid, n1 = tid + 256;
            const int m0 = n0 & 15, m1 = n1 & 15;
            float b0 = 0.f, b1 = 0.f, b2 = 0.f, b3 = 0.f,
                  b4 = 0.f, b5 = 0.f, b6 = 0.f, b7 = 0.f;
            float c0 = 0.f, c1 = 0.f, c2 = 0.f, c3 = 0.f,
                  c4 = 0.f, c5 = 0.f, c6 = 0.f, c7 = 0.f;
            #pragma unroll 4
            for (int qd = 0; qd < 16; ++qd) {      // lo half from LDS
                float4 e0 = *(const float4*)&sm.EA[n0 * 64 + ((qd ^ m0) << 2)];
                float4 e1 = *(const float4*)&sm.EA[n1 * 64 + ((qd ^ m1) << 2)];
#define CH(h_, bb_, cc_) { float4 qv = *(const float4*)&sm.qt[h_ * DD + qd * 4]; \
                bb_ += dot4(qv, e0); cc_ += dot4(qv, e1); }
                CH(0, b0, c0) CH(1, b1, c1) CH(2, b2, c2) CH(3, b3, c3)
                CH(4, b4, c4) CH(5, b5, c5) CH(6, b6, c6) CH(7, b7, c7)
#undef CH
            }
            #pragma unroll 4
            for (int qd = 0; qd < 16; ++qd) {      // hi half from global
                float4 e0 = Ef4[n0 * 32 + 16 + qd];
                float4 e1 = Ef4[n1 * 32 + 16 + qd];
#define CH(h_, bb_, cc_) { float4 qv = *(const float4*)&sm.qt[h_ * DD + 64 + qd * 4]; \
                bb_ += dot4(qv, e0); cc_ += dot4(qv, e1); }
                CH(0, b0, c0) CH(1, b1, c1) CH(2, b2, c2) CH(3, b3, c3)
                CH(4, b4, c4) CH(5, b5, c5) CH(6, b6, c6) CH(7, b7, c7)
#undef CH
            }
            const bool v0 = (sm.visf[n0] != 0), v1 = (sm.visf[n1] != 0);
            float4 P0a, P0b, P1a, P1b;
            P0a.x = v0 ? 0.f : expf(b0 - mh0);
            P0a.y = v0 ? 0.f : expf(b1 - mh1);
            P0a.z = v0 ? 0.f : expf(b2 - mh2);
            P0a.w = v0 ? 0.f : expf(b3 - mh3);
            P0b.x = v0 ? 0.f : expf(b4 - mh4);
            P0b.y = v0 ? 0.f : expf(b5 - mh5);
            P0b.z = v0 ? 0.f : expf(b6 - mh6);
            P0b.w = v0 ? 0.f : expf(b7 - mh7);
            P1a.x = v1 ? 0.f : expf(c0 - mh0);
            P1a.y = v1 ? 0.f : expf(c1 - mh1);
            P1a.z = v1 ? 0.f : expf(c2 - mh2);
            P1a.w = v1 ? 0.f : expf(c3 - mh3);
            P1b.x = v1 ? 0.f : expf(c4 - mh4);
            P1b.y = v1 ? 0.f : expf(c5 - mh5);
            P1b.z = v1 ? 0.f : expf(c6 - mh6);
            P1b.w = v1 ? 0.f : expf(c7 - mh7);
            *(float4*)&sm.Pt[n0 * 12]     = P0a;
            *(float4*)&sm.Pt[n0 * 12 + 4] = P0b;
            *(float4*)&sm.Pt[n1 * 12]     = P1a;
            *(float4*)&sm.Pt[n1 * 12 + 4] = P1b;
        }
        __syncthreads();                                               // B3

        // ---- l[h] (wave h) + e-bar accumulate (r12 verbatim, stride 12) ----
        {
            const int h = wv;
            float sl = 0.f;
            #pragma unroll
            for (int i = 0; i < 8; ++i) sl += sm.Pt[(lane + i * 64) * 12 + h];
            for (int o = 1; o < 64; o <<= 1) sl += __shfl_xor(sl, o);
            if (lane == 0) sm.l[h] = sl;
        }
        const int dq = tid & 31, ch = tid >> 5;    // d-quad, 32-row chunk
        float4 a0 = {0,0,0,0}, a1 = {0,0,0,0}, a2 = {0,0,0,0}, a3 = {0,0,0,0},
               a4 = {0,0,0,0}, a5 = {0,0,0,0}, a6 = {0,0,0,0}, a7 = {0,0,0,0};
        {
            const int r0 = ch * 32;
            #pragma unroll 2
            for (int i = 0; i < 32; ++i) {
                const int r = r0 + i;
                float4 ev = (dq < 16)
                    ? *(const float4*)&sm.EA[r * 64 + ((dq ^ (r & 15)) << 2)]
                    : Ef4[r * 32 + dq];
                float4 pA = *(const float4*)&sm.Pt[r * 12];
                float4 pB = *(const float4*)&sm.Pt[r * 12 + 4];
                fma4(a0, pA.x, ev); fma4(a1, pA.y, ev);
                fma4(a2, pA.z, ev); fma4(a3, pA.w, ev);
                fma4(a4, pB.x, ev); fma4(a5, pB.y, ev);
                fma4(a6, pB.z, ev); fma4(a7, pB.w, ev);
            }
        }
        __syncthreads();                          // B4: P dead, slots alias ok
        {   // staged partial combine: 4 rounds into 4 slots (r12 verbatim)
            const int slot = ch & 3, rnd = ch >> 2;
            #pragma unroll
            for (int rr = 0; rr < 4; ++rr) {
                if (rnd == rr) {
                    float* sp = slots + (size_t)slot * 1024 + dq * 4;
                    if (rr == 0) {
#define STW(h_, av_) *(float4*)&sp[h_ * 128] = av_;
                        STW(0, a0) STW(1, a1) STW(2, a2) STW(3, a3)
                        STW(4, a4) STW(5, a5) STW(6, a6) STW(7, a7)
#undef STW
                    } else {
#define STA(h_, av_) { float4 tv = *(float4*)&sp[h_ * 128];                  \
                        tv.x += av_.x; tv.y += av_.y; tv.z += av_.z; tv.w += av_.w; \
                        *(float4*)&sp[h_ * 128] = tv; }
                        STA(0, a0) STA(1, a1) STA(2, a2) STA(3, a3)
                        STA(4, a4) STA(5, a5) STA(6, a6) STA(7, a7)
#undef STA
                    }
                }
                __syncthreads();                                       // B5-B8
            }
        }
        {   // combine 4 slots -> eb[h][d] normalized (eb aliases qt)
            const int h = tid >> 6, d2 = (tid & 63) * 2;
            float inv = 1.0f / sm.l[h];
            #pragma unroll
            for (int r = 0; r < 2; ++r) {
                int d = d2 + r;
                float a = slots[0 * 1024 + h * 128 + d] + slots[1 * 1024 + h * 128 + d]
                        + slots[2 * 1024 + h * 128 + d] + slots[3 * 1024 + h * 128 + d];
                ebp[h * 128 + d] = a * inv;
            }
        }
        __syncthreads();                                               // B9

        // ---- hc partials = eb @ Wv (r12 verbatim) ----
        {
            float s = 0.f;
            int k0 = g4 * 32;
            const int hh = d128 >> 4;
            const float* Wv = Wn + 128 + d128;
            #pragma unroll 8
            for (int d = k0; d < k0 + 32; ++d) s += ebp[hh * 128 + d] * Wv[d * 384];
            part[g4 * 128 + d128] = s;
        }
        __syncthreads();                                               // B10
        // ---- g' partials = hc @ Wog; hc inlined via broadcasts ----
        {
            float s = 0.f;
            int k0 = g4 * 32;
            #pragma unroll 8
            for (int k = k0; k < k0 + 32; ++k) {
                float hck = part[0 * 128 + k] + part[1 * 128 + k]
                          + part[2 * 128 + k] + part[3 * 128 + k];
                s += hck * Wog[k * DD + d128];
            }
            part2[g4 * 128 + d128] = s;
        }
        __syncthreads();                                               // B11
        // ---- logits: thread n; gs inlined via float4 broadcasts ----
        {
            const int n = tid, nm = n & 15;
            float s = 0.f;
            #pragma unroll 4
            for (int qd = 0; qd < 16; ++qd) {
                float4 p0 = *(const float4*)&part2[0 * 128 + qd * 4];
                float4 p1 = *(const float4*)&part2[1 * 128 + qd * 4];
                float4 p2 = *(const float4*)&part2[2 * 128 + qd * 4];
                float4 p3 = *(const float4*)&part2[3 * 128 + qd * 4];
                float4 gq;
                gq.x = (p0.x + p1.x + p2.x + p3.x) * INV_SQRT_D;
                gq.y = (p0.y + p1.y + p2.y + p3.y) * INV_SQRT_D;
                gq.z = (p0.z + p1.z + p2.z + p3.z) * INV_SQRT_D;
                gq.w = (p0.w + p1.w + p2.w + p3.w) * INV_SQRT_D;
                float4 ev = *(const float4*)&sm.EA[n * 64 + ((qd ^ nm) << 2)];
                s += dot4(gq, ev);
            }
            #pragma unroll 4
            for (int qd = 0; qd < 16; ++qd) {
                const int i0 = 64 + qd * 4;
                float4 p0 = *(const float4*)&part2[0 * 128 + i0];
                float4 p1 = *(const float4*)&part2[1 * 128 + i0];
                float4 p2 = *(const float4*)&part2[2 * 128 + i0];
                float4 p3 = *(const float4*)&part2[3 * 128 + i0];
                float4 gq;
                gq.x = (p0.x + p1.x + p2.x + p3.x) * INV_SQRT_D;
                gq.y = (p0.y + p1.y + p2.y + p3.y) * INV_SQRT_D;
                gq.z = (p0.z + p1.z + p2.z + p3.z) * INV_SQRT_D;
                gq.w = (p0.w + p1.w + p2.w + p3.w) * INV_SQRT_D;
                float4 ev = Ef4[n * 32 + 16 + qd];
                s += dot4(gq, ev);
            }
            lgp[n] = sm.visf[n] ? NEGC : 10.0f * tanhf(s);
        }
        __syncthreads();                                               // B12

        // ---- stats + argmax, redundantly in ALL waves (deterministic);
        //      store fused; no trailing barrier ----
        {
            float x0 = lgp[lane],       x1 = lgp[lane + 64],
                  x2 = lgp[lane + 128], x3 = lgp[lane + 192],
                  x4 = lgp[lane + 256], x5 = lgp[lane + 320],
                  x6 = lgp[lane + 384], x7 = lgp[lane + 448];
            float m = fmaxf(fmaxf(fmaxf(x0, x1), fmaxf(x2, x3)),
                            fmaxf(fmaxf(x4, x5), fmaxf(x6, x7)));
            for (int o = 1; o < 64; o <<= 1) m = fmaxf(m, __shfl_xor(m, o));
            float ssum = expf(x0 - m) + expf(x1 - m) + expf(x2 - m) + expf(x3 - m)
                       + expf(x4 - m) + expf(x5 - m) + expf(x6 - m) + expf(x7 - m);
            for (int o = 1; o < 64; o <<= 1) ssum += __shfl_xor(ssum, o);
            float lse = logf(ssum);
            float bv = (x0 - m) - lse; int bi = lane;
#define AMX(xi, ii) { float v_ = ((xi) - m) - lse; int i_ = (ii);           \
            if (v_ > bv) { bv = v_; bi = i_; } }
            AMX(x1, lane + 64)  AMX(x2, lane + 128) AMX(x3, lane + 192)
            AMX(x4, lane + 256) AMX(x5, lane + 320) AMX(x6, lane + 384)
            AMX(x7, lane + 448)
#undef AMX
            for (int o = 1; o < 64; o <<= 1) {
                float ov = __shfl_xor(bv, o);
                int   oi = __shfl_xor(bi, o);
                if (ov > bv || (ov == bv && oi < bi)) { bv = ov; bi = oi; }
            }
            cur = bi;                              // every thread agrees
            float lp = (lgp[tid] - m) - lse;
            out_logp[((size_t)b * T + t) * NN + tid] = lp;
            if (wv == 0 && lane == 0) out_seq[(size_t)b * T + t] = (float)bi;
            if (tid == cur) sm.visf[tid] = 1;      // visible after next B1/B2
        }
    }
}

// ------------------------------- launcher -----------------------------------
extern "C" void kernel_launch(void* const* d_in, const int* in_sizes, int n_in,
                              void* d_out, int out_size, void* d_ws, size_t ws_size,
                              hipStream_t stream) {
    const float* E    = (const float*)d_in[0];   // [B,N,D]
    const float* Wn   = (const float*)d_in[1];   // [D,3D]
    const float* Wf   = (const float*)d_in[2];   // [D,D]
    const float* Ws   = (const float*)d_in[3];   // [D+1,D]
    const float* Wout = (const float*)d_in[4];   // [D,D]
    float* out = (float*)d_out;

    const int T = out_size / (BB * (NN + 1));    // = num_steps (64)

    float* fcp = (float*)d_ws;                   // [B,D]
    float* Wog = fcp + BB * DD;                  // [128,128]
    float* WkT = Wog + DD * DD;                  // [128,128]

    precompute_fc<<<BB, 128, 0, stream>>>(E, Wf, fcp);
    precompute_w<<<DD, 128, 0, stream>>>(Wn, Wout, Wog, WkT);
    decoder<<<BB, 512, 0, stream>>>(E, Ws, Wn, fcp, Wog, WkT,
                                    out, out + (size_t)BB * T * NN, T);
}

// Round 17
// 2032.204 us; speedup vs baseline: 2.0328x; 1.0885x over previous
//
#include <hip/hip_runtime.h>

#define BB 256
#define NN 512
#define DD 128
#define HH 8

static constexpr float NEGC = -1e9f;
static constexpr float INV_SQRT_D = 0.08838834764831845f; // 1/sqrt(128)

__device__ __forceinline__ float dot4(float4 a, float4 b) {
    return a.x * b.x + a.y * b.y + a.z * b.z + a.w * b.w;
}
__device__ __forceinline__ void fma4(float4& a, float p, float4 e) {
    a.x += p * e.x; a.y += p * e.y; a.z += p * e.z; a.w += p * e.w;
}

// ---------------- precompute: fixed_ctx = mean_n(E) @ W_fixed ----------------
__global__ __launch_bounds__(128)
void precompute_fc(const float* __restrict__ E, const float* __restrict__ Wf,
                   float* __restrict__ fc) {
    int b = blockIdx.x, d = threadIdx.x;
    __shared__ float ge[DD];
    const float* Eb = E + (size_t)b * NN * DD;
    float s = 0.f;
    for (int n = 0; n < NN; ++n) s += Eb[n * DD + d];
    ge[d] = s * (1.0f / 512.0f);
    __syncthreads();
    float o = 0.f;
    for (int k = 0; k < DD; ++k) o += ge[k] * Wf[k * DD + d];
    fc[b * DD + d] = o;
}

// ---- precompute: WkT[k][d] = W_node[d][k] (k<128);  W_og = W_out @ Wl^T ----
__global__ __launch_bounds__(128)
void precompute_w(const float* __restrict__ Wn, const float* __restrict__ Wout,
                  float* __restrict__ Wog, float* __restrict__ WkT) {
    int k = blockIdx.x, d = threadIdx.x;
    WkT[k * DD + d] = Wn[d * 384 + k];
    float s = 0.f;
    for (int e = 0; e < DD; ++e) s += Wout[k * DD + e] * Wn[d * 384 + 256 + e];
    Wog[k * DD + d] = s;
}

// ---------------------------- main decoder ----------------------------------
// v18 = r12 (2055us champion) + ONLY the individually-validated deltas:
//  1) curE eliminated: phase0 reads E[cur] from global via per-thread register
//     `cur` (r15/r16-validated); trailing barrier dropped.
//  2) Pt stride 8 -> 12 (r15/r16-validated; conflicts 1.41e8 -> 1.16e8).
//  3) stats+argmax redundantly in ALL waves (deterministic; r16-validated),
//     fused with store: stats barrier + sm.stat/sm.cur round-trips gone.
// Everything else r12-VERBATIM (compat 2-row tiling, e-bar 4-round slot
// combine, separate qarr/Mh/hc/gs combine phases).  Barriers: 18 -> 16.
// NOT repeated: Wvog fusion (r15: +L2 traffic > barrier win), combine
// inlining (r16: duplicated broadcasts > barrier win).
struct SMw18 {
    float EA[NN * 64];    // 131072 B  E-lo, row n quad q at (q^(n&15))
    float Pt[NN * 12];    // 24576 B   P[n][.]; aliases: slots[4][8][128]@0,
                          //           part[4][128]@0, lgp[512]@4096 floats
    float qt[HH * DD];    // 4096 B    q~; alias eb[8][128] after compat
    float qarr[DD];
    float fcs[DD];
    float hcv[DD];
    float gs[DD];
    float l[HH];
    float Mh[HH];
    float redf[16];
    unsigned char visf[NN];
    float rbv;
};

__global__ __launch_bounds__(512)
void decoder(const float* __restrict__ E, const float* __restrict__ Ws,
             const float* __restrict__ Wn, const float* __restrict__ fc,
             const float* __restrict__ Wog, const float* __restrict__ WkT,
             float* __restrict__ out_logp, float* __restrict__ out_seq, int T) {
    __shared__ SMw18 sm;
    const int b = blockIdx.x, tid = threadIdx.x;
    const int lane = tid & 63, wv = tid >> 6;
    const int g4 = tid >> 7, d128 = tid & 127;
    const float* Eg = E + (size_t)b * NN * DD;
    const float4* Ef4 = (const float4*)Eg;

    float* const slots = &sm.Pt[0];            // [4][8][128] after P dies
    float* const part  = &sm.Pt[0];            // [4][128] small-phase partials
    float* const lgp   = &sm.Pt[4096];         // [512] logits
    float* const ebp   = &sm.qt[0];            // eb[8][128] after qt dies

    // ---- init: EA (E-lo swizzled, coalesced), fcs, visf, rbv ----
    #pragma unroll
    for (int i = 0; i < 16; ++i) {
        int f = i * 512 + tid;
        int nn = f >> 4, cq = f & 15;
        *(float4*)&sm.EA[nn * 64 + ((cq ^ (nn & 15)) << 2)] = Ef4[nn * 32 + cq];
    }
    if (tid < DD) sm.fcs[tid] = fc[b * DD + tid];
    sm.visf[tid] = 0;
    int cur = 0;                               // per-thread; all threads agree
    {
        float s = 0.f;
        #pragma unroll 8
        for (int i = 0; i < 32; ++i) { float4 v = Ef4[tid * 32 + i]; s += dot4(v, v); }
        for (int o = 1; o < 64; o <<= 1) s = fmaxf(s, __shfl_xor(s, o));
        if (lane == 0) sm.redf[wv] = s;
    }
    __syncthreads();
    if (tid == 0) {
        float m = sm.redf[0];
        for (int i = 1; i < 8; ++i) m = fmaxf(m, sm.redf[i]);
        sm.rbv = sqrtf(m);
    }
    __syncthreads();

    for (int t = 0; t < T; ++t) {
        // ---- phase 0: q-partials = E[cur]@Ws + frac*Ws_last (E[cur] global) ----
        {
            const float* Ecur = Eg + (size_t)cur * DD;
            const float* Wsg = Ws + d128;
            float s = 0.f;
            int k0 = g4 * 32;
            #pragma unroll 8
            for (int k = k0; k < k0 + 32; ++k) s += Ecur[k] * Wsg[k * DD];
            if (g4 == 3) s += ((float)t / (float)T) * Wsg[DD * DD];
            part[g4 * 128 + d128] = s;
        }
        __syncthreads();                                               // B1
        if (tid < DD)
            sm.qarr[tid] = sm.fcs[tid] + part[0 * 128 + tid] + part[1 * 128 + tid]
                         + part[2 * 128 + tid] + part[3 * 128 + tid];
        __syncthreads();                                               // B2
        // ---- qt (0.25 folded) + Cauchy-Schwarz norms (r12 verbatim) ----
        {
            const int hA = g4, hB = g4 + 4;
            const float* WA = WkT + (hA * 16) * DD + d128;
            const float* WB = WkT + (hB * 16) * DD + d128;
            float a = 0.f, c = 0.f;
            #pragma unroll
            for (int j = 0; j < 16; ++j) {
                a += sm.qarr[hA * 16 + j] * WA[j * DD];
                c += sm.qarr[hB * 16 + j] * WB[j * DD];
            }
            a *= 0.25f; c *= 0.25f;
            sm.qt[hA * DD + d128] = a;
            sm.qt[hB * DD + d128] = c;
            float sa = a * a, sc = c * c;
            for (int o = 1; o < 64; o <<= 1) {
                sa += __shfl_xor(sa, o);
                sc += __shfl_xor(sc, o);
            }
            if (lane == 0) { sm.redf[wv] = sa; sm.redf[8 + wv] = sc; }
        }
        __syncthreads();                                               // B3
        if (tid < 8) {
            int h = tid;
            float ss = (h < 4) ? (sm.redf[2 * h] + sm.redf[2 * h + 1])
                               : (sm.redf[8 + 2 * (h - 4)] + sm.redf[8 + 2 * (h - 4) + 1]);
            sm.Mh[h] = sqrtf(ss) * sm.rbv;
        }
        __syncthreads();                                               // B4

        // ---- compat: 2 rows/thread (tid<256), r12 verbatim; Pt stride 12 ----
        if (tid < 256) {
            const int n0 = tid, n1 = tid + 256;
            const int m0 = n0 & 15, m1 = n1 & 15;
            float b0 = 0.f, b1 = 0.f, b2 = 0.f, b3 = 0.f,
                  b4 = 0.f, b5 = 0.f, b6 = 0.f, b7 = 0.f;
            float c0 = 0.f, c1 = 0.f, c2 = 0.f, c3 = 0.f,
                  c4 = 0.f, c5 = 0.f, c6 = 0.f, c7 = 0.f;
            #pragma unroll 4
            for (int qd = 0; qd < 16; ++qd) {      // lo half from LDS
                float4 e0 = *(const float4*)&sm.EA[n0 * 64 + ((qd ^ m0) << 2)];
                float4 e1 = *(const float4*)&sm.EA[n1 * 64 + ((qd ^ m1) << 2)];
#define CH(h_, bb_, cc_) { float4 qv = *(const float4*)&sm.qt[h_ * DD + qd * 4]; \
                bb_ += dot4(qv, e0); cc_ += dot4(qv, e1); }
                CH(0, b0, c0) CH(1, b1, c1) CH(2, b2, c2) CH(3, b3, c3)
                CH(4, b4, c4) CH(5, b5, c5) CH(6, b6, c6) CH(7, b7, c7)
#undef CH
            }
            #pragma unroll 4
            for (int qd = 0; qd < 16; ++qd) {      // hi half from global
                float4 e0 = Ef4[n0 * 32 + 16 + qd];
                float4 e1 = Ef4[n1 * 32 + 16 + qd];
#define CH(h_, bb_, cc_) { float4 qv = *(const float4*)&sm.qt[h_ * DD + 64 + qd * 4]; \
                bb_ += dot4(qv, e0); cc_ += dot4(qv, e1); }
                CH(0, b0, c0) CH(1, b1, c1) CH(2, b2, c2) CH(3, b3, c3)
                CH(4, b4, c4) CH(5, b5, c5) CH(6, b6, c6) CH(7, b7, c7)
#undef CH
            }
            const bool v0 = (sm.visf[n0] != 0), v1 = (sm.visf[n1] != 0);
            float4 P0a, P0b, P1a, P1b;
            P0a.x = v0 ? 0.f : expf(b0 - sm.Mh[0]);
            P0a.y = v0 ? 0.f : expf(b1 - sm.Mh[1]);
            P0a.z = v0 ? 0.f : expf(b2 - sm.Mh[2]);
            P0a.w = v0 ? 0.f : expf(b3 - sm.Mh[3]);
            P0b.x = v0 ? 0.f : expf(b4 - sm.Mh[4]);
            P0b.y = v0 ? 0.f : expf(b5 - sm.Mh[5]);
            P0b.z = v0 ? 0.f : expf(b6 - sm.Mh[6]);
            P0b.w = v0 ? 0.f : expf(b7 - sm.Mh[7]);
            P1a.x = v1 ? 0.f : expf(c0 - sm.Mh[0]);
            P1a.y = v1 ? 0.f : expf(c1 - sm.Mh[1]);
            P1a.z = v1 ? 0.f : expf(c2 - sm.Mh[2]);
            P1a.w = v1 ? 0.f : expf(c3 - sm.Mh[3]);
            P1b.x = v1 ? 0.f : expf(c4 - sm.Mh[4]);
            P1b.y = v1 ? 0.f : expf(c5 - sm.Mh[5]);
            P1b.z = v1 ? 0.f : expf(c6 - sm.Mh[6]);
            P1b.w = v1 ? 0.f : expf(c7 - sm.Mh[7]);
            *(float4*)&sm.Pt[n0 * 12]     = P0a;
            *(float4*)&sm.Pt[n0 * 12 + 4] = P0b;
            *(float4*)&sm.Pt[n1 * 12]     = P1a;
            *(float4*)&sm.Pt[n1 * 12 + 4] = P1b;
        }
        __syncthreads();                                               // B5

        // ---- l[h] (wave h) + e-bar accumulate (r12 verbatim, stride 12) ----
        {
            const int h = wv;
            float sl = 0.f;
            #pragma unroll
            for (int i = 0; i < 8; ++i) sl += sm.Pt[(lane + i * 64) * 12 + h];
            for (int o = 1; o < 64; o <<= 1) sl += __shfl_xor(sl, o);
            if (lane == 0) sm.l[h] = sl;
        }
        const int dq = tid & 31, ch = tid >> 5;    // d-quad, 32-row chunk
        float4 a0 = {0,0,0,0}, a1 = {0,0,0,0}, a2 = {0,0,0,0}, a3 = {0,0,0,0},
               a4 = {0,0,0,0}, a5 = {0,0,0,0}, a6 = {0,0,0,0}, a7 = {0,0,0,0};
        {
            const int r0 = ch * 32;
            #pragma unroll 2
            for (int i = 0; i < 32; ++i) {
                const int r = r0 + i;
                float4 ev = (dq < 16)
                    ? *(const float4*)&sm.EA[r * 64 + ((dq ^ (r & 15)) << 2)]
                    : Ef4[r * 32 + dq];
                float4 pA = *(const float4*)&sm.Pt[r * 12];
                float4 pB = *(const float4*)&sm.Pt[r * 12 + 4];
                fma4(a0, pA.x, ev); fma4(a1, pA.y, ev);
                fma4(a2, pA.z, ev); fma4(a3, pA.w, ev);
                fma4(a4, pB.x, ev); fma4(a5, pB.y, ev);
                fma4(a6, pB.z, ev); fma4(a7, pB.w, ev);
            }
        }
        __syncthreads();                          // B6: P dead, slots alias ok
        {   // staged partial combine: 4 rounds into 4 slots (r12 verbatim)
            const int slot = ch & 3, rnd = ch >> 2;
            #pragma unroll
            for (int rr = 0; rr < 4; ++rr) {
                if (rnd == rr) {
                    float* sp = slots + (size_t)slot * 1024 + dq * 4;
                    if (rr == 0) {
#define STW(h_, av_) *(float4*)&sp[h_ * 128] = av_;
                        STW(0, a0) STW(1, a1) STW(2, a2) STW(3, a3)
                        STW(4, a4) STW(5, a5) STW(6, a6) STW(7, a7)
#undef STW
                    } else {
#define STA(h_, av_) { float4 tv = *(float4*)&sp[h_ * 128];                  \
                        tv.x += av_.x; tv.y += av_.y; tv.z += av_.z; tv.w += av_.w; \
                        *(float4*)&sp[h_ * 128] = tv; }
                        STA(0, a0) STA(1, a1) STA(2, a2) STA(3, a3)
                        STA(4, a4) STA(5, a5) STA(6, a6) STA(7, a7)
#undef STA
                    }
                }
                __syncthreads();                                       // B7-B10
            }
        }
        {   // combine 4 slots -> eb[h][d] normalized (eb aliases qt)
            const int h = tid >> 6, d2 = (tid & 63) * 2;
            float inv = 1.0f / sm.l[h];
            #pragma unroll
            for (int r = 0; r < 2; ++r) {
                int d = d2 + r;
                float a = slots[0 * 1024 + h * 128 + d] + slots[1 * 1024 + h * 128 + d]
                        + slots[2 * 1024 + h * 128 + d] + slots[3 * 1024 + h * 128 + d];
                ebp[h * 128 + d] = a * inv;
            }
        }
        __syncthreads();                                               // B11

        // ---- hc = eb @ Wv (r12 verbatim) ----
        {
            float s = 0.f;
            int k0 = g4 * 32;
            const int hh = d128 >> 4;
            const float* Wv = Wn + 128 + d128;
            #pragma unroll 8
            for (int d = k0; d < k0 + 32; ++d) s += ebp[hh * 128 + d] * Wv[d * 384];
            part[g4 * 128 + d128] = s;
        }
        __syncthreads();                                               // B12
        if (tid < DD)
            sm.hcv[tid] = part[0 * 128 + tid] + part[1 * 128 + tid]
                        + part[2 * 128 + tid] + part[3 * 128 + tid];
        __syncthreads();                                               // B13
        // ---- g~ = (hc @ Wog) * inv_sqrt_D (r12 verbatim) ----
        {
            float s = 0.f;
            int k0 = g4 * 32;
            #pragma unroll 8
            for (int k = k0; k < k0 + 32; ++k) s += sm.hcv[k] * Wog[k * DD + d128];
            part[g4 * 128 + d128] = s;
        }
        __syncthreads();                                               // B14
        if (tid < DD)
            sm.gs[tid] = (part[0 * 128 + tid] + part[1 * 128 + tid]
                        + part[2 * 128 + tid] + part[3 * 128 + tid]) * INV_SQRT_D;
        __syncthreads();                                               // B15

        // ---- logits: thread n = g~ . E[n] (lo LDS, hi global; r12 verbatim) ----
        {
            const int n = tid, nm = n & 15;
            float s = 0.f;
            #pragma unroll 4
            for (int qd = 0; qd < 16; ++qd) {
                float4 gq = *(const float4*)&sm.gs[qd * 4];
                float4 ev = *(const float4*)&sm.EA[n * 64 + ((qd ^ nm) << 2)];
                s += dot4(gq, ev);
            }
            #pragma unroll 4
            for (int qd = 0; qd < 16; ++qd) {
                float4 gq = *(const float4*)&sm.gs[64 + qd * 4];
                float4 ev = Ef4[n * 32 + 16 + qd];
                s += dot4(gq, ev);
            }
            lgp[n] = sm.visf[n] ? NEGC : 10.0f * tanhf(s);
        }
        __syncthreads();                                               // B16

        // ---- stats + argmax redundantly in ALL waves (r16-validated);
        //      store fused; no trailing barrier ----
        {
            float x0 = lgp[lane],       x1 = lgp[lane + 64],
                  x2 = lgp[lane + 128], x3 = lgp[lane + 192],
                  x4 = lgp[lane + 256], x5 = lgp[lane + 320],
                  x6 = lgp[lane + 384], x7 = lgp[lane + 448];
            float m = fmaxf(fmaxf(fmaxf(x0, x1), fmaxf(x2, x3)),
                            fmaxf(fmaxf(x4, x5), fmaxf(x6, x7)));
            for (int o = 1; o < 64; o <<= 1) m = fmaxf(m, __shfl_xor(m, o));
            float ssum = expf(x0 - m) + expf(x1 - m) + expf(x2 - m) + expf(x3 - m)
                       + expf(x4 - m) + expf(x5 - m) + expf(x6 - m) + expf(x7 - m);
            for (int o = 1; o < 64; o <<= 1) ssum += __shfl_xor(ssum, o);
            float lse = logf(ssum);
            float bv = (x0 - m) - lse; int bi = lane;
#define AMX(xi, ii) { float v_ = ((xi) - m) - lse; int i_ = (ii);           \
            if (v_ > bv) { bv = v_; bi = i_; } }
            AMX(x1, lane + 64)  AMX(x2, lane + 128) AMX(x3, lane + 192)
            AMX(x4, lane + 256) AMX(x5, lane + 320) AMX(x6, lane + 384)
            AMX(x7, lane + 448)
#undef AMX
            for (int o = 1; o < 64; o <<= 1) {
                float ov = __shfl_xor(bv, o);
                int   oi = __shfl_xor(bi, o);
                if (ov > bv || (ov == bv && oi < bi)) { bv = ov; bi = oi; }
            }
            cur = bi;                              // identical in every thread
            float lp = (lgp[tid] - m) - lse;
            out_logp[((size_t)b * T + t) * NN + tid] = lp;
            if (tid == 0) out_seq[(size_t)b * T + t] = (float)bi;
            if (tid == cur) sm.visf[tid] = 1;      // next read after B1/B2
        }
    }
}

// ------------------------------- launcher -----------------------------------
extern "C" void kernel_launch(void* const* d_in, const int* in_sizes, int n_in,
                              void* d_out, int out_size, void* d_ws, size_t ws_size,
                              hipStream_t stream) {
    const float* E    = (const float*)d_in[0];   // [B,N,D]
    const float* Wn   = (const float*)d_in[1];   // [D,3D]
    const float* Wf   = (const float*)d_in[2];   // [D,D]
    const float* Ws   = (const float*)d_in[3];   // [D+1,D]
    const float* Wout = (const float*)d_in[4];   // [D,D]
    float* out = (float*)d_out;

    const int T = out_size / (BB * (NN + 1));    // = num_steps (64)

    float* fcp = (float*)d_ws;                   // [B,D]
    float* Wog = fcp + BB * DD;                  // [128,128]
    float* WkT = Wog + DD * DD;                  // [128,128]

    precompute_fc<<<BB, 128, 0, stream>>>(E, Wf, fcp);
    precompute_w<<<DD, 128, 0, stream>>>(Wn, Wout, Wog, WkT);
    decoder<<<BB, 512, 0, stream>>>(E, Ws, Wn, fcp, Wog, WkT,
                                    out, out + (size_t)BB * T * NN, T);
}

// Round 18
// 2003.460 us; speedup vs baseline: 2.0620x; 1.0143x over previous
//
#include <hip/hip_runtime.h>

#define BB 256
#define NN 512
#define DD 128
#define HH 8

static constexpr float NEGC = -1e9f;
static constexpr float INV_SQRT_D = 0.08838834764831845f; // 1/sqrt(128)

__device__ __forceinline__ float dot4(float4 a, float4 b) {
    return a.x * b.x + a.y * b.y + a.z * b.z + a.w * b.w;
}
__device__ __forceinline__ void fma4(float4& a, float p, float4 e) {
    a.x += p * e.x; a.y += p * e.y; a.z += p * e.z; a.w += p * e.w;
}

// ---------------- precompute: fixed_ctx = mean_n(E) @ W_fixed ----------------
__global__ __launch_bounds__(128)
void precompute_fc(const float* __restrict__ E, const float* __restrict__ Wf,
                   float* __restrict__ fc) {
    int b = blockIdx.x, d = threadIdx.x;
    __shared__ float ge[DD];
    const float* Eb = E + (size_t)b * NN * DD;
    float s = 0.f;
    for (int n = 0; n < NN; ++n) s += Eb[n * DD + d];
    ge[d] = s * (1.0f / 512.0f);
    __syncthreads();
    float o = 0.f;
    for (int k = 0; k < DD; ++k) o += ge[k] * Wf[k * DD + d];
    fc[b * DD + d] = o;
}

// ---- precompute: WkT[k][d] = W_node[d][k] (k<128);  W_og = W_out @ Wl^T ----
__global__ __launch_bounds__(128)
void precompute_w(const float* __restrict__ Wn, const float* __restrict__ Wout,
                  float* __restrict__ Wog, float* __restrict__ WkT) {
    int k = blockIdx.x, d = threadIdx.x;
    WkT[k * DD + d] = Wn[d * 384 + k];
    float s = 0.f;
    for (int e = 0; e < DD; ++e) s += Wout[k * DD + e] * Wn[d * 384 + 256 + e];
    Wog[k * DD + d] = s;
}

// ---------------------------- main decoder ----------------------------------
// v19 = r17 (2032us champion) + two latency-hiding fixes, values BIT-IDENTICAL:
//  1) compat on ALL 512 threads, 1 row/thread (was 256 threads / 2 rows):
//     qt LDS reads are lane-invariant broadcasts (cheap), so the 2-row
//     amortization bought nothing; 4 waves -> 8 waves doubles latency hiding
//     during the heaviest global-load phase. Per-row accumulation order is
//     r12's exact sequence -> P bit-identical.
//  2) e-bar LDS/global split made WAVE-UNIFORM: waves 0-3 = dq 0-15 (pure
//     LDS), waves 4-7 = dq 16-31 (pure global). Same (dq,ch) work-item set,
//     same slot/round combine mapping (slot=ch&3 rnd=ch>>2, still uniform:
//     rnd == wv&3) -> e-bar bit-identical.
// Everything else r17-verbatim.
struct SMw19 {
    float EA[NN * 64];    // 131072 B  E-lo, row n quad q at (q^(n&15))
    float Pt[NN * 12];    // 24576 B   P[n][.]; aliases: slots[4][8][128]@0,
                          //           part[4][128]@0, lgp[512]@4096 floats
    float qt[HH * DD];    // 4096 B    q~; alias eb[8][128] after compat
    float qarr[DD];
    float fcs[DD];
    float hcv[DD];
    float gs[DD];
    float l[HH];
    float Mh[HH];
    float redf[16];
    unsigned char visf[NN];
    float rbv;
};

__global__ __launch_bounds__(512)
void decoder(const float* __restrict__ E, const float* __restrict__ Ws,
             const float* __restrict__ Wn, const float* __restrict__ fc,
             const float* __restrict__ Wog, const float* __restrict__ WkT,
             float* __restrict__ out_logp, float* __restrict__ out_seq, int T) {
    __shared__ SMw19 sm;
    const int b = blockIdx.x, tid = threadIdx.x;
    const int lane = tid & 63, wv = tid >> 6;
    const int g4 = tid >> 7, d128 = tid & 127;
    const float* Eg = E + (size_t)b * NN * DD;
    const float4* Ef4 = (const float4*)Eg;

    float* const slots = &sm.Pt[0];            // [4][8][128] after P dies
    float* const part  = &sm.Pt[0];            // [4][128] small-phase partials
    float* const lgp   = &sm.Pt[4096];         // [512] logits
    float* const ebp   = &sm.qt[0];            // eb[8][128] after qt dies

    // ---- init: EA (E-lo swizzled, coalesced), fcs, visf, rbv ----
    #pragma unroll
    for (int i = 0; i < 16; ++i) {
        int f = i * 512 + tid;
        int nn = f >> 4, cq = f & 15;
        *(float4*)&sm.EA[nn * 64 + ((cq ^ (nn & 15)) << 2)] = Ef4[nn * 32 + cq];
    }
    if (tid < DD) sm.fcs[tid] = fc[b * DD + tid];
    sm.visf[tid] = 0;
    int cur = 0;                               // per-thread; all threads agree
    {
        float s = 0.f;
        #pragma unroll 8
        for (int i = 0; i < 32; ++i) { float4 v = Ef4[tid * 32 + i]; s += dot4(v, v); }
        for (int o = 1; o < 64; o <<= 1) s = fmaxf(s, __shfl_xor(s, o));
        if (lane == 0) sm.redf[wv] = s;
    }
    __syncthreads();
    if (tid == 0) {
        float m = sm.redf[0];
        for (int i = 1; i < 8; ++i) m = fmaxf(m, sm.redf[i]);
        sm.rbv = sqrtf(m);
    }
    __syncthreads();

    for (int t = 0; t < T; ++t) {
        // ---- phase 0: q-partials = E[cur]@Ws + frac*Ws_last (E[cur] global) ----
        {
            const float* Ecur = Eg + (size_t)cur * DD;
            const float* Wsg = Ws + d128;
            float s = 0.f;
            int k0 = g4 * 32;
            #pragma unroll 8
            for (int k = k0; k < k0 + 32; ++k) s += Ecur[k] * Wsg[k * DD];
            if (g4 == 3) s += ((float)t / (float)T) * Wsg[DD * DD];
            part[g4 * 128 + d128] = s;
        }
        __syncthreads();                                               // B1
        if (tid < DD)
            sm.qarr[tid] = sm.fcs[tid] + part[0 * 128 + tid] + part[1 * 128 + tid]
                         + part[2 * 128 + tid] + part[3 * 128 + tid];
        __syncthreads();                                               // B2
        // ---- qt (0.25 folded) + Cauchy-Schwarz norms (r12 verbatim) ----
        {
            const int hA = g4, hB = g4 + 4;
            const float* WA = WkT + (hA * 16) * DD + d128;
            const float* WB = WkT + (hB * 16) * DD + d128;
            float a = 0.f, c = 0.f;
            #pragma unroll
            for (int j = 0; j < 16; ++j) {
                a += sm.qarr[hA * 16 + j] * WA[j * DD];
                c += sm.qarr[hB * 16 + j] * WB[j * DD];
            }
            a *= 0.25f; c *= 0.25f;
            sm.qt[hA * DD + d128] = a;
            sm.qt[hB * DD + d128] = c;
            float sa = a * a, sc = c * c;
            for (int o = 1; o < 64; o <<= 1) {
                sa += __shfl_xor(sa, o);
                sc += __shfl_xor(sc, o);
            }
            if (lane == 0) { sm.redf[wv] = sa; sm.redf[8 + wv] = sc; }
        }
        __syncthreads();                                               // B3
        if (tid < 8) {
            int h = tid;
            float ss = (h < 4) ? (sm.redf[2 * h] + sm.redf[2 * h + 1])
                               : (sm.redf[8 + 2 * (h - 4)] + sm.redf[8 + 2 * (h - 4) + 1]);
            sm.Mh[h] = sqrtf(ss) * sm.rbv;
        }
        __syncthreads();                                               // B4

        // ---- compat: ALL 512 threads, 1 row each (r12's per-row order) ----
        {
            const int n0 = tid;
            const int m0 = n0 & 15;
            float b0 = 0.f, b1 = 0.f, b2 = 0.f, b3 = 0.f,
                  b4 = 0.f, b5 = 0.f, b6 = 0.f, b7 = 0.f;
            #pragma unroll 4
            for (int qd = 0; qd < 16; ++qd) {      // lo half from LDS
                float4 e0 = *(const float4*)&sm.EA[n0 * 64 + ((qd ^ m0) << 2)];
#define CH(h_, bb_) { float4 qv = *(const float4*)&sm.qt[h_ * DD + qd * 4];  \
                bb_ += dot4(qv, e0); }
                CH(0, b0) CH(1, b1) CH(2, b2) CH(3, b3)
                CH(4, b4) CH(5, b5) CH(6, b6) CH(7, b7)
#undef CH
            }
            #pragma unroll 4
            for (int qd = 0; qd < 16; ++qd) {      // hi half from global
                float4 e0 = Ef4[n0 * 32 + 16 + qd];
#define CH(h_, bb_) { float4 qv = *(const float4*)&sm.qt[h_ * DD + 64 + qd * 4]; \
                bb_ += dot4(qv, e0); }
                CH(0, b0) CH(1, b1) CH(2, b2) CH(3, b3)
                CH(4, b4) CH(5, b5) CH(6, b6) CH(7, b7)
#undef CH
            }
            const bool v0 = (sm.visf[n0] != 0);
            float4 P0a, P0b;
            P0a.x = v0 ? 0.f : expf(b0 - sm.Mh[0]);
            P0a.y = v0 ? 0.f : expf(b1 - sm.Mh[1]);
            P0a.z = v0 ? 0.f : expf(b2 - sm.Mh[2]);
            P0a.w = v0 ? 0.f : expf(b3 - sm.Mh[3]);
            P0b.x = v0 ? 0.f : expf(b4 - sm.Mh[4]);
            P0b.y = v0 ? 0.f : expf(b5 - sm.Mh[5]);
            P0b.z = v0 ? 0.f : expf(b6 - sm.Mh[6]);
            P0b.w = v0 ? 0.f : expf(b7 - sm.Mh[7]);
            *(float4*)&sm.Pt[n0 * 12]     = P0a;
            *(float4*)&sm.Pt[n0 * 12 + 4] = P0b;
        }
        __syncthreads();                                               // B5

        // ---- l[h] (wave h) + e-bar accumulate (wave-uniform LDS/global) ----
        {
            const int h = wv;
            float sl = 0.f;
            #pragma unroll
            for (int i = 0; i < 8; ++i) sl += sm.Pt[(lane + i * 64) * 12 + h];
            for (int o = 1; o < 64; o <<= 1) sl += __shfl_xor(sl, o);
            if (lane == 0) sm.l[h] = sl;
        }
        // work item (dq, ch): waves 0-3 -> dq = lane&15 (LDS), ch = (wv&3)*4+(lane>>4)
        //                     waves 4-7 -> dq = 16+(lane&15) (global), same ch
        const int isG = wv >> 2;
        const int dq = isG * 16 + (lane & 15);
        const int ch = (wv & 3) * 4 + (lane >> 4);
        float4 a0 = {0,0,0,0}, a1 = {0,0,0,0}, a2 = {0,0,0,0}, a3 = {0,0,0,0},
               a4 = {0,0,0,0}, a5 = {0,0,0,0}, a6 = {0,0,0,0}, a7 = {0,0,0,0};
        {
            const int r0 = ch * 32;
            if (isG == 0) {
                #pragma unroll 2
                for (int i = 0; i < 32; ++i) {
                    const int r = r0 + i;
                    float4 ev = *(const float4*)&sm.EA[r * 64 + ((dq ^ (r & 15)) << 2)];
                    float4 pA = *(const float4*)&sm.Pt[r * 12];
                    float4 pB = *(const float4*)&sm.Pt[r * 12 + 4];
                    fma4(a0, pA.x, ev); fma4(a1, pA.y, ev);
                    fma4(a2, pA.z, ev); fma4(a3, pA.w, ev);
                    fma4(a4, pB.x, ev); fma4(a5, pB.y, ev);
                    fma4(a6, pB.z, ev); fma4(a7, pB.w, ev);
                }
            } else {
                #pragma unroll 2
                for (int i = 0; i < 32; ++i) {
                    const int r = r0 + i;
                    float4 ev = Ef4[r * 32 + dq];
                    float4 pA = *(const float4*)&sm.Pt[r * 12];
                    float4 pB = *(const float4*)&sm.Pt[r * 12 + 4];
                    fma4(a0, pA.x, ev); fma4(a1, pA.y, ev);
                    fma4(a2, pA.z, ev); fma4(a3, pA.w, ev);
                    fma4(a4, pB.x, ev); fma4(a5, pB.y, ev);
                    fma4(a6, pB.z, ev); fma4(a7, pB.w, ev);
                }
            }
        }
        __syncthreads();                          // B6: P dead, slots alias ok
        {   // staged partial combine: 4 rounds into 4 slots (rnd = ch>>2 = wv&3)
            const int slot = ch & 3, rnd = ch >> 2;
            #pragma unroll
            for (int rr = 0; rr < 4; ++rr) {
                if (rnd == rr) {
                    float* sp = slots + (size_t)slot * 1024 + dq * 4;
                    if (rr == 0) {
#define STW(h_, av_) *(float4*)&sp[h_ * 128] = av_;
                        STW(0, a0) STW(1, a1) STW(2, a2) STW(3, a3)
                        STW(4, a4) STW(5, a5) STW(6, a6) STW(7, a7)
#undef STW
                    } else {
#define STA(h_, av_) { float4 tv = *(float4*)&sp[h_ * 128];                  \
                        tv.x += av_.x; tv.y += av_.y; tv.z += av_.z; tv.w += av_.w; \
                        *(float4*)&sp[h_ * 128] = tv; }
                        STA(0, a0) STA(1, a1) STA(2, a2) STA(3, a3)
                        STA(4, a4) STA(5, a5) STA(6, a6) STA(7, a7)
#undef STA
                    }
                }
                __syncthreads();                                       // B7-B10
            }
        }
        {   // combine 4 slots -> eb[h][d] normalized (eb aliases qt)
            const int h = tid >> 6, d2 = (tid & 63) * 2;
            float inv = 1.0f / sm.l[h];
            #pragma unroll
            for (int r = 0; r < 2; ++r) {
                int d = d2 + r;
                float a = slots[0 * 1024 + h * 128 + d] + slots[1 * 1024 + h * 128 + d]
                        + slots[2 * 1024 + h * 128 + d] + slots[3 * 1024 + h * 128 + d];
                ebp[h * 128 + d] = a * inv;
            }
        }
        __syncthreads();                                               // B11

        // ---- hc = eb @ Wv (r12 verbatim) ----
        {
            float s = 0.f;
            int k0 = g4 * 32;
            const int hh = d128 >> 4;
            const float* Wv = Wn + 128 + d128;
            #pragma unroll 8
            for (int d = k0; d < k0 + 32; ++d) s += ebp[hh * 128 + d] * Wv[d * 384];
            part[g4 * 128 + d128] = s;
        }
        __syncthreads();                                               // B12
        if (tid < DD)
            sm.hcv[tid] = part[0 * 128 + tid] + part[1 * 128 + tid]
                        + part[2 * 128 + tid] + part[3 * 128 + tid];
        __syncthreads();                                               // B13
        // ---- g~ = (hc @ Wog) * inv_sqrt_D (r12 verbatim) ----
        {
            float s = 0.f;
            int k0 = g4 * 32;
            #pragma unroll 8
            for (int k = k0; k < k0 + 32; ++k) s += sm.hcv[k] * Wog[k * DD + d128];
            part[g4 * 128 + d128] = s;
        }
        __syncthreads();                                               // B14
        if (tid < DD)
            sm.gs[tid] = (part[0 * 128 + tid] + part[1 * 128 + tid]
                        + part[2 * 128 + tid] + part[3 * 128 + tid]) * INV_SQRT_D;
        __syncthreads();                                               // B15

        // ---- logits: thread n = g~ . E[n] (lo LDS, hi global; r12 verbatim) ----
        {
            const int n = tid, nm = n & 15;
            float s = 0.f;
            #pragma unroll 4
            for (int qd = 0; qd < 16; ++qd) {
                float4 gq = *(const float4*)&sm.gs[qd * 4];
                float4 ev = *(const float4*)&sm.EA[n * 64 + ((qd ^ nm) << 2)];
                s += dot4(gq, ev);
            }
            #pragma unroll 4
            for (int qd = 0; qd < 16; ++qd) {
                float4 gq = *(const float4*)&sm.gs[64 + qd * 4];
                float4 ev = Ef4[n * 32 + 16 + qd];
                s += dot4(gq, ev);
            }
            lgp[n] = sm.visf[n] ? NEGC : 10.0f * tanhf(s);
        }
        __syncthreads();                                               // B16

        // ---- stats + argmax redundantly in ALL waves; store fused ----
        {
            float x0 = lgp[lane],       x1 = lgp[lane + 64],
                  x2 = lgp[lane + 128], x3 = lgp[lane + 192],
                  x4 = lgp[lane + 256], x5 = lgp[lane + 320],
                  x6 = lgp[lane + 384], x7 = lgp[lane + 448];
            float m = fmaxf(fmaxf(fmaxf(x0, x1), fmaxf(x2, x3)),
                            fmaxf(fmaxf(x4, x5), fmaxf(x6, x7)));
            for (int o = 1; o < 64; o <<= 1) m = fmaxf(m, __shfl_xor(m, o));
            float ssum = expf(x0 - m) + expf(x1 - m) + expf(x2 - m) + expf(x3 - m)
                       + expf(x4 - m) + expf(x5 - m) + expf(x6 - m) + expf(x7 - m);
            for (int o = 1; o < 64; o <<= 1) ssum += __shfl_xor(ssum, o);
            float lse = logf(ssum);
            float bv = (x0 - m) - lse; int bi = lane;
#define AMX(xi, ii) { float v_ = ((xi) - m) - lse; int i_ = (ii);           \
            if (v_ > bv) { bv = v_; bi = i_; } }
            AMX(x1, lane + 64)  AMX(x2, lane + 128) AMX(x3, lane + 192)
            AMX(x4, lane + 256) AMX(x5, lane + 320) AMX(x6, lane + 384)
            AMX(x7, lane + 448)
#undef AMX
            for (int o = 1; o < 64; o <<= 1) {
                float ov = __shfl_xor(bv, o);
                int   oi = __shfl_xor(bi, o);
                if (ov > bv || (ov == bv && oi < bi)) { bv = ov; bi = oi; }
            }
            cur = bi;                              // identical in every thread
            float lp = (lgp[tid] - m) - lse;
            out_logp[((size_t)b * T + t) * NN + tid] = lp;
            if (tid == 0) out_seq[(size_t)b * T + t] = (float)bi;
            if (tid == cur) sm.visf[tid] = 1;      // next read after B1/B2
        }
    }
}

// ------------------------------- launcher -----------------------------------
extern "C" void kernel_launch(void* const* d_in, const int* in_sizes, int n_in,
                              void* d_out, int out_size, void* d_ws, size_t ws_size,
                              hipStream_t stream) {
    const float* E    = (const float*)d_in[0];   // [B,N,D]
    const float* Wn   = (const float*)d_in[1];   // [D,3D]
    const float* Wf   = (const float*)d_in[2];   // [D,D]
    const float* Ws   = (const float*)d_in[3];   // [D+1,D]
    const float* Wout = (const float*)d_in[4];   // [D,D]
    float* out = (float*)d_out;

    const int T = out_size / (BB * (NN + 1));    // = num_steps (64)

    float* fcp = (float*)d_ws;                   // [B,D]
    float* Wog = fcp + BB * DD;                  // [128,128]
    float* WkT = Wog + DD * DD;                  // [128,128]

    precompute_fc<<<BB, 128, 0, stream>>>(E, Wf, fcp);
    precompute_w<<<DD, 128, 0, stream>>>(Wn, Wout, Wog, WkT);
    decoder<<<BB, 512, 0, stream>>>(E, Ws, Wn, fcp, Wog, WkT,
                                    out, out + (size_t)BB * T * NN, T);
}